// Round 1
// baseline (1967.362 us; speedup 1.0000x reference)
//
#include <hip/hip_runtime.h>
#include <math.h>

#define SB 1024   // seq len
#define DM 1024   // d_model
#define BB 4      // batch
#define NH 16     // heads
#define DH 64     // head dim
#define ML 1024   // MAX_LEN

// ---------------- sinusoidal positional encoding ----------------
__global__ void pe_kernel(float* __restrict__ pe) {
  int p = blockIdx.x;
  for (int i = threadIdx.x; i < DM / 2; i += 256) {
    float div = expf((float)(2 * i) * (-9.210340371976184f / (float)DM));
    float ang = (float)p * div;
    pe[(size_t)p * DM + 2 * i]     = sinf(ang);
    pe[(size_t)p * DM + 2 * i + 1] = cosf(ang);
  }
}

// ---------------- layernorm ----------------
__device__ __forceinline__ float block_sum256(float s, float* red) {
  #pragma unroll
  for (int o = 32; o > 0; o >>= 1) s += __shfl_down(s, o, 64);
  int t = threadIdx.x;
  if ((t & 63) == 0) red[t >> 6] = s;
  __syncthreads();
  float tot = red[0] + red[1] + red[2] + red[3];
  __syncthreads();
  return tot;
}

__global__ __launch_bounds__(256) void ln_kernel(const float* __restrict__ x,
    const float* __restrict__ gamma, const float* __restrict__ beta,
    float* __restrict__ xn) {
  __shared__ float red[4];
  int row = blockIdx.x;  // 0..B*S-1
  const float4* xr = (const float4*)(x + (size_t)row * DM);
  int t = threadIdx.x;
  float4 v = xr[t];
  float mu = block_sum256(v.x + v.y + v.z + v.w, red) * (1.0f / DM);
  float4 d = {v.x - mu, v.y - mu, v.z - mu, v.w - mu};
  float var = block_sum256(d.x*d.x + d.y*d.y + d.z*d.z + d.w*d.w, red) * (1.0f / DM);
  float rstd = rsqrtf(var + 1e-5f);
  float4 g  = ((const float4*)gamma)[t];
  float4 bb = ((const float4*)beta)[t];
  float4 o = {d.x * rstd * g.x + bb.x, d.y * rstd * g.y + bb.y,
              d.z * rstd * g.z + bb.z, d.w * rstd * g.w + bb.w};
  ((float4*)(xn + (size_t)row * DM))[t] = o;
}

// ---------------- fp32 GEMM: C[M,N] = A[M,K] * W[N,K]^T ----------------
#define BM 128
#define BN 128
#define BK 16

__global__ __launch_bounds__(256) void gemm_nt(const float* __restrict__ A,
    const float* __restrict__ W, float* __restrict__ C,
    int M, int N, int K) {
  __shared__ float As[BK][BM + 4];
  __shared__ float Ws[BK][BN + 4];
  int m0 = blockIdx.y * BM;
  int n0 = blockIdx.x * BN;
  int t = threadIdx.x;
  int tx = t & 15, ty = t >> 4;
  float acc[8][8];
  #pragma unroll
  for (int i = 0; i < 8; ++i)
    #pragma unroll
    for (int j = 0; j < 8; ++j) acc[i][j] = 0.f;

  for (int kt = 0; kt < K; kt += BK) {
    #pragma unroll
    for (int l = 0; l < 2; ++l) {
      int idx = t + l * 256;        // 0..511
      int r = idx >> 2;             // 0..127
      int kc = (idx & 3) << 2;      // 0,4,8,12
      float4 av = *(const float4*)(A + (size_t)(m0 + r) * K + kt + kc);
      As[kc + 0][r] = av.x; As[kc + 1][r] = av.y;
      As[kc + 2][r] = av.z; As[kc + 3][r] = av.w;
      float4 wv = *(const float4*)(W + (size_t)(n0 + r) * K + kt + kc);
      Ws[kc + 0][r] = wv.x; Ws[kc + 1][r] = wv.y;
      Ws[kc + 2][r] = wv.z; Ws[kc + 3][r] = wv.w;
    }
    __syncthreads();
    #pragma unroll
    for (int kk = 0; kk < BK; ++kk) {
      float4 a0 = *(const float4*)&As[kk][ty * 8];
      float4 a1 = *(const float4*)&As[kk][ty * 8 + 4];
      float4 w0 = *(const float4*)&Ws[kk][tx * 8];
      float4 w1 = *(const float4*)&Ws[kk][tx * 8 + 4];
      float a_[8] = {a0.x, a0.y, a0.z, a0.w, a1.x, a1.y, a1.z, a1.w};
      float w_[8] = {w0.x, w0.y, w0.z, w0.w, w1.x, w1.y, w1.z, w1.w};
      #pragma unroll
      for (int i = 0; i < 8; ++i)
        #pragma unroll
        for (int j = 0; j < 8; ++j)
          acc[i][j] = fmaf(a_[i], w_[j], acc[i][j]);
    }
    __syncthreads();
  }
  #pragma unroll
  for (int i = 0; i < 8; ++i) {
    float4 o0 = {acc[i][0], acc[i][1], acc[i][2], acc[i][3]};
    float4 o1 = {acc[i][4], acc[i][5], acc[i][6], acc[i][7]};
    float* cp = C + (size_t)(m0 + ty * 8 + i) * N + n0 + tx * 8;
    *(float4*)cp = o0;
    *(float4*)(cp + 4) = o1;
  }
}

// ---------------- fused attention ----------------
// One block handles (b, h, 8 q-rows). Logit row (len 1024) lives in LDS.
// QK is a fused 128-dim dot: [tok_q || pos_q] . [tok_k || pos_k].
#define QR 8

__global__ __launch_bounds__(256) void attn_kernel(
    const float* __restrict__ tok,   // [B,S,3D] : k | q | v
    const float* __restrict__ pos,   // [S,2D]   : pos_k | pos_q
    const float* __restrict__ bt,    // [2*ML, H]
    float* __restrict__ out) {       // [B,S,D]
  __shared__ float Qc[QR][132];      // combined q fragment, 128 used
  __shared__ float Lg[QR][SB];       // logits -> probs
  __shared__ float inv_sum[QR];
  int bid = blockIdx.x;
  int qt = bid & (SB / QR - 1);      // 128 q-tiles
  int h  = (bid >> 7) & (NH - 1);
  int b  = bid >> 11;
  int q0 = qt * QR;
  int t = threadIdx.x;

  { // load Qc: QR rows x 32 float4
    int r = t >> 5, d4 = t & 31;
    int q = q0 + r;
    float4 v;
    if (d4 < 16)
      v = *(const float4*)(tok + (size_t)(b * SB + q) * (3 * DM) + DM + h * DH + d4 * 4);
    else
      v = *(const float4*)(pos + (size_t)q * (2 * DM) + DM + h * DH + (d4 - 16) * 4);
    *(float4*)&Qc[r][d4 * 4] = v;
  }
  __syncthreads();

  // ---- phase 1: logits. thread t owns k in {t, t+256, t+512, t+768} ----
  {
    float acc[4][QR];
    #pragma unroll
    for (int s2 = 0; s2 < 4; ++s2)
      #pragma unroll
      for (int r = 0; r < QR; ++r) acc[s2][r] = 0.f;
    const float* Kt = tok + (size_t)(b * SB) * (3 * DM) + h * DH;
    const float* Kp = pos + h * DH;
    #pragma unroll 4
    for (int d4 = 0; d4 < 32; ++d4) {
      float4 kv[4];
      #pragma unroll
      for (int s2 = 0; s2 < 4; ++s2) {
        int k = t + s2 * 256;
        kv[s2] = (d4 < 16)
          ? *(const float4*)(Kt + (size_t)k * (3 * DM) + d4 * 4)
          : *(const float4*)(Kp + (size_t)k * (2 * DM) + (d4 - 16) * 4);
      }
      #pragma unroll
      for (int r = 0; r < QR; ++r) {
        float4 qv = *(const float4*)&Qc[r][d4 * 4];
        #pragma unroll
        for (int s2 = 0; s2 < 4; ++s2) {
          acc[s2][r] = fmaf(qv.x, kv[s2].x, acc[s2][r]);
          acc[s2][r] = fmaf(qv.y, kv[s2].y, acc[s2][r]);
          acc[s2][r] = fmaf(qv.z, kv[s2].z, acc[s2][r]);
          acc[s2][r] = fmaf(qv.w, kv[s2].w, acc[s2][r]);
        }
      }
    }
    const float IS = 11.313708498984761f;  // sqrt(2*dh): reference DIVIDES by 1/sqrt(2dh)
    #pragma unroll
    for (int s2 = 0; s2 < 4; ++s2) {
      int k = t + s2 * 256;
      #pragma unroll
      for (int r = 0; r < QR; ++r) {
        int rel = k - (q0 + r) + ML;   // in [1, 2047]
        Lg[r][k] = acc[s2][r] * IS + bt[rel * NH + h];
      }
    }
  }
  __syncthreads();

  // ---- phase 2: softmax per row (4 waves x 2 rows) ----
  {
    int wv = t >> 6, lane = t & 63;
    #pragma unroll
    for (int rr = 0; rr < QR / 4; ++rr) {
      int r = wv * (QR / 4) + rr;
      float m = -INFINITY;
      for (int k = lane; k < SB; k += 64) m = fmaxf(m, Lg[r][k]);
      #pragma unroll
      for (int o = 32; o > 0; o >>= 1) m = fmaxf(m, __shfl_xor(m, o, 64));
      float ss = 0.f;
      for (int k = lane; k < SB; k += 64) {
        float e = expf(Lg[r][k] - m);
        Lg[r][k] = e;
        ss += e;
      }
      #pragma unroll
      for (int o = 32; o > 0; o >>= 1) ss += __shfl_xor(ss, o, 64);
      if (lane == 0) inv_sum[r] = 1.0f / ss;
    }
  }
  __syncthreads();

  // ---- phase 3: PV. thread -> (r = t>>5, dp = t&31), float2 over d ----
  {
    int r = t >> 5, dp = t & 31;
    const float* V = tok + (size_t)(b * SB) * (3 * DM) + 2 * DM + h * DH + dp * 2;
    float2 o = {0.f, 0.f};
    for (int k = 0; k < SB; ++k) {
      float p = Lg[r][k];
      float2 vv = *(const float2*)(V + (size_t)k * (3 * DM));
      o.x = fmaf(p, vv.x, o.x);
      o.y = fmaf(p, vv.y, o.y);
    }
    float is = inv_sum[r];
    o.x *= is; o.y *= is;
    *(float2*)(out + (size_t)(b * SB + q0 + r) * DM + h * DH + dp * 2) = o;
  }
}

extern "C" void kernel_launch(void* const* d_in, const int* in_sizes, int n_in,
                              void* d_out, int out_size, void* d_ws, size_t ws_size,
                              hipStream_t stream) {
  const float* x     = (const float*)d_in[0];
  const float* gamma = (const float*)d_in[1];
  const float* beta  = (const float*)d_in[2];
  const float* w_pos = (const float*)d_in[3];
  const float* w_tok = (const float*)d_in[4];
  const float* bt    = (const float*)d_in[5];
  float* out = (float*)d_out;
  float* ws  = (float*)d_ws;

  float* pe  = ws;                        // 1M floats  (4 MB)
  float* pos = ws + (1u << 20);           // 2M floats  (8 MB)
  float* xn  = ws + 3u * (1u << 20);      // 4M floats  (16 MB)
  float* tok = ws + 7u * (1u << 20);      // 12M floats (48 MB)

  pe_kernel<<<SB, 256, 0, stream>>>(pe);
  ln_kernel<<<BB * SB, 256, 0, stream>>>(x, gamma, beta, xn);
  // pos = pe @ w_pos^T : [1024, 2048]
  gemm_nt<<<dim3((2 * DM) / BN, SB / BM), 256, 0, stream>>>(pe, w_pos, pos, SB, 2 * DM, DM);
  // tok = xn @ w_tok^T : [4096, 3072]
  gemm_nt<<<dim3((3 * DM) / BN, (BB * SB) / BM), 256, 0, stream>>>(xn, w_tok, tok, BB * SB, 3 * DM, DM);
  attn_kernel<<<BB * NH * (SB / QR), 256, 0, stream>>>(tok, pos, bt, out);
}

// Round 2
// 1679.539 us; speedup vs baseline: 1.1714x; 1.1714x over previous
//
#include <hip/hip_runtime.h>
#include <math.h>

#define SB 1024   // seq len
#define DM 1024   // d_model
#define BB 4      // batch
#define NH 16     // heads
#define DH 64     // head dim
#define ML 1024   // MAX_LEN

// ---------------- sinusoidal positional encoding ----------------
__global__ void pe_kernel(float* __restrict__ pe) {
  int p = blockIdx.x;
  for (int i = threadIdx.x; i < DM / 2; i += 256) {
    float div = expf((float)(2 * i) * (-9.210340371976184f / (float)DM));
    float ang = (float)p * div;
    pe[(size_t)p * DM + 2 * i]     = sinf(ang);
    pe[(size_t)p * DM + 2 * i + 1] = cosf(ang);
  }
}

// ---------------- layernorm ----------------
__device__ __forceinline__ float block_sum256(float s, float* red) {
  #pragma unroll
  for (int o = 32; o > 0; o >>= 1) s += __shfl_down(s, o, 64);
  int t = threadIdx.x;
  if ((t & 63) == 0) red[t >> 6] = s;
  __syncthreads();
  float tot = red[0] + red[1] + red[2] + red[3];
  __syncthreads();
  return tot;
}

__global__ __launch_bounds__(256) void ln_kernel(const float* __restrict__ x,
    const float* __restrict__ gamma, const float* __restrict__ beta,
    float* __restrict__ xn) {
  __shared__ float red[4];
  int row = blockIdx.x;  // 0..B*S-1
  const float4* xr = (const float4*)(x + (size_t)row * DM);
  int t = threadIdx.x;
  float4 v = xr[t];
  float mu = block_sum256(v.x + v.y + v.z + v.w, red) * (1.0f / DM);
  float4 d = {v.x - mu, v.y - mu, v.z - mu, v.w - mu};
  float var = block_sum256(d.x*d.x + d.y*d.y + d.z*d.z + d.w*d.w, red) * (1.0f / DM);
  float rstd = rsqrtf(var + 1e-5f);
  float4 g  = ((const float4*)gamma)[t];
  float4 bb = ((const float4*)beta)[t];
  float4 o = {d.x * rstd * g.x + bb.x, d.y * rstd * g.y + bb.y,
              d.z * rstd * g.z + bb.z, d.w * rstd * g.w + bb.w};
  ((float4*)(xn + (size_t)row * DM))[t] = o;
}

// ---------------- fp32 GEMM: C[M,N] = A[M,K] * W[N,K]^T ----------------
#define BM 128
#define BN 128
#define BK 16

__global__ __launch_bounds__(256) void gemm_nt(const float* __restrict__ A,
    const float* __restrict__ W, float* __restrict__ C,
    int M, int N, int K) {
  __shared__ float As[BK][BM + 4];
  __shared__ float Ws[BK][BN + 4];
  int m0 = blockIdx.y * BM;
  int n0 = blockIdx.x * BN;
  int t = threadIdx.x;
  int tx = t & 15, ty = t >> 4;
  float acc[8][8];
  #pragma unroll
  for (int i = 0; i < 8; ++i)
    #pragma unroll
    for (int j = 0; j < 8; ++j) acc[i][j] = 0.f;

  for (int kt = 0; kt < K; kt += BK) {
    #pragma unroll
    for (int l = 0; l < 2; ++l) {
      int idx = t + l * 256;        // 0..511
      int r = idx >> 2;             // 0..127
      int kc = (idx & 3) << 2;      // 0,4,8,12
      float4 av = *(const float4*)(A + (size_t)(m0 + r) * K + kt + kc);
      As[kc + 0][r] = av.x; As[kc + 1][r] = av.y;
      As[kc + 2][r] = av.z; As[kc + 3][r] = av.w;
      float4 wv = *(const float4*)(W + (size_t)(n0 + r) * K + kt + kc);
      Ws[kc + 0][r] = wv.x; Ws[kc + 1][r] = wv.y;
      Ws[kc + 2][r] = wv.z; Ws[kc + 3][r] = wv.w;
    }
    __syncthreads();
    #pragma unroll
    for (int kk = 0; kk < BK; ++kk) {
      float4 a0 = *(const float4*)&As[kk][ty * 8];
      float4 a1 = *(const float4*)&As[kk][ty * 8 + 4];
      float4 w0 = *(const float4*)&Ws[kk][tx * 8];
      float4 w1 = *(const float4*)&Ws[kk][tx * 8 + 4];
      float a_[8] = {a0.x, a0.y, a0.z, a0.w, a1.x, a1.y, a1.z, a1.w};
      float w_[8] = {w0.x, w0.y, w0.z, w0.w, w1.x, w1.y, w1.z, w1.w};
      #pragma unroll
      for (int i = 0; i < 8; ++i)
        #pragma unroll
        for (int j = 0; j < 8; ++j)
          acc[i][j] = fmaf(a_[i], w_[j], acc[i][j]);
    }
    __syncthreads();
  }
  #pragma unroll
  for (int i = 0; i < 8; ++i) {
    float4 o0 = {acc[i][0], acc[i][1], acc[i][2], acc[i][3]};
    float4 o1 = {acc[i][4], acc[i][5], acc[i][6], acc[i][7]};
    float* cp = C + (size_t)(m0 + ty * 8 + i) * N + n0 + tx * 8;
    *(float4*)cp = o0;
    *(float4*)(cp + 4) = o1;
  }
}

// ---------------- pack K into d-major (s-contiguous) layout ----------------
// Kt[b][h][d][s] = tok_k[b][s][h*64+d]      (z = 0..BB-1 -> b)
// Kp[h][d][s]    = pos_k[s][h*64+d]         (z = BB)
__global__ __launch_bounds__(256) void pack_k_kernel(
    const float* __restrict__ tok, const float* __restrict__ pos,
    float* __restrict__ Kt, float* __restrict__ Kp) {
  __shared__ float Ts[64][65];
  int st = blockIdx.x;          // s-tile (16)
  int h  = blockIdx.y;          // head
  int z  = blockIdx.z;          // 0..BB-1: tok part; BB: pos part
  int t = threadIdx.x;
  int s0 = st * 64;

  // read 64 s x 64 d tile, coalesced along d
  #pragma unroll
  for (int it = 0; it < 4; ++it) {
    int s = it * 16 + (t >> 4);
    int d4 = t & 15;
    float4 v;
    if (z < BB)
      v = *(const float4*)(tok + (size_t)((z * SB + s0 + s)) * (3 * DM) + h * DH + d4 * 4);
    else
      v = *(const float4*)(pos + (size_t)(s0 + s) * (2 * DM) + h * DH + d4 * 4);
    Ts[s][d4 * 4 + 0] = v.x; Ts[s][d4 * 4 + 1] = v.y;
    Ts[s][d4 * 4 + 2] = v.z; Ts[s][d4 * 4 + 3] = v.w;
  }
  __syncthreads();

  // write transposed: d-major, s contiguous
  float* outp = (z < BB) ? (Kt + (size_t)((z * NH + h) * 64) * SB)
                         : (Kp + (size_t)(h * 64) * SB);
  #pragma unroll
  for (int it = 0; it < 4; ++it) {
    int d = it * 16 + (t >> 4);
    int s4 = t & 15;
    float4 o = {Ts[s4 * 4 + 0][d], Ts[s4 * 4 + 1][d],
                Ts[s4 * 4 + 2][d], Ts[s4 * 4 + 3][d]};
    *(float4*)(outp + (size_t)d * SB + s0 + s4 * 4) = o;
  }
}

// ---------------- fused attention ----------------
// One block handles (b, h, 8 q-rows). Logit row (len 1024) lives in LDS.
// QK is a fused 128-dim dot: [tok_q || pos_q] . [tok_k || pos_k].
// K comes from the packed d-major buffers -> coalesced k-contiguous loads.
#define QR 8

__global__ __launch_bounds__(256) void attn_kernel(
    const float* __restrict__ tok,   // [B,S,3D] : k | q | v
    const float* __restrict__ pos,   // [S,2D]   : pos_k | pos_q
    const float* __restrict__ Kt,    // [B,H,64,S]
    const float* __restrict__ Kp,    // [H,64,S]
    const float* __restrict__ bt,    // [2*ML, H]
    float* __restrict__ out) {       // [B,S,D]
  __shared__ float Qc[QR][132];      // combined q fragment, 128 used
  __shared__ float Lg[QR][SB];       // logits -> probs
  __shared__ float inv_sum[QR];
  int bid = blockIdx.x;
  int qt = bid & (SB / QR - 1);      // 128 q-tiles
  int h  = (bid >> 7) & (NH - 1);
  int b  = bid >> 11;
  int q0 = qt * QR;
  int t = threadIdx.x;

  { // load Qc: QR rows x 32 float4 (small, once)
    int r = t >> 5, d4 = t & 31;
    int q = q0 + r;
    float4 v;
    if (d4 < 16)
      v = *(const float4*)(tok + (size_t)(b * SB + q) * (3 * DM) + DM + h * DH + d4 * 4);
    else
      v = *(const float4*)(pos + (size_t)q * (2 * DM) + DM + h * DH + (d4 - 16) * 4);
    *(float4*)&Qc[r][d4 * 4] = v;
  }
  __syncthreads();

  // ---- phase 1: logits. thread t owns k = 4t..4t+3 (coalesced K loads) ----
  {
    float4 acc[QR];
    #pragma unroll
    for (int r = 0; r < QR; ++r) acc[r] = {0.f, 0.f, 0.f, 0.f};

    const float* Ktb = Kt + (size_t)((b * NH + h) * 64) * SB + 4 * t;
    const float* Kpb = Kp + (size_t)(h * 64) * SB + 4 * t;

    #pragma unroll 2
    for (int d4 = 0; d4 < 16; ++d4) {   // tok_k dims 0..63
      float4 kv0 = *(const float4*)(Ktb + (size_t)(d4 * 4 + 0) * SB);
      float4 kv1 = *(const float4*)(Ktb + (size_t)(d4 * 4 + 1) * SB);
      float4 kv2 = *(const float4*)(Ktb + (size_t)(d4 * 4 + 2) * SB);
      float4 kv3 = *(const float4*)(Ktb + (size_t)(d4 * 4 + 3) * SB);
      #pragma unroll
      for (int r = 0; r < QR; ++r) {
        float4 qv = *(const float4*)&Qc[r][d4 * 4];
        acc[r].x = fmaf(qv.x, kv0.x, acc[r].x); acc[r].y = fmaf(qv.x, kv0.y, acc[r].y);
        acc[r].z = fmaf(qv.x, kv0.z, acc[r].z); acc[r].w = fmaf(qv.x, kv0.w, acc[r].w);
        acc[r].x = fmaf(qv.y, kv1.x, acc[r].x); acc[r].y = fmaf(qv.y, kv1.y, acc[r].y);
        acc[r].z = fmaf(qv.y, kv1.z, acc[r].z); acc[r].w = fmaf(qv.y, kv1.w, acc[r].w);
        acc[r].x = fmaf(qv.z, kv2.x, acc[r].x); acc[r].y = fmaf(qv.z, kv2.y, acc[r].y);
        acc[r].z = fmaf(qv.z, kv2.z, acc[r].z); acc[r].w = fmaf(qv.z, kv2.w, acc[r].w);
        acc[r].x = fmaf(qv.w, kv3.x, acc[r].x); acc[r].y = fmaf(qv.w, kv3.y, acc[r].y);
        acc[r].z = fmaf(qv.w, kv3.z, acc[r].z); acc[r].w = fmaf(qv.w, kv3.w, acc[r].w);
      }
    }
    #pragma unroll 2
    for (int d4 = 0; d4 < 16; ++d4) {   // pos_k dims 64..127
      float4 kv0 = *(const float4*)(Kpb + (size_t)(d4 * 4 + 0) * SB);
      float4 kv1 = *(const float4*)(Kpb + (size_t)(d4 * 4 + 1) * SB);
      float4 kv2 = *(const float4*)(Kpb + (size_t)(d4 * 4 + 2) * SB);
      float4 kv3 = *(const float4*)(Kpb + (size_t)(d4 * 4 + 3) * SB);
      #pragma unroll
      for (int r = 0; r < QR; ++r) {
        float4 qv = *(const float4*)&Qc[r][64 + d4 * 4];
        acc[r].x = fmaf(qv.x, kv0.x, acc[r].x); acc[r].y = fmaf(qv.x, kv0.y, acc[r].y);
        acc[r].z = fmaf(qv.x, kv0.z, acc[r].z); acc[r].w = fmaf(qv.x, kv0.w, acc[r].w);
        acc[r].x = fmaf(qv.y, kv1.x, acc[r].x); acc[r].y = fmaf(qv.y, kv1.y, acc[r].y);
        acc[r].z = fmaf(qv.y, kv1.z, acc[r].z); acc[r].w = fmaf(qv.y, kv1.w, acc[r].w);
        acc[r].x = fmaf(qv.z, kv2.x, acc[r].x); acc[r].y = fmaf(qv.z, kv2.y, acc[r].y);
        acc[r].z = fmaf(qv.z, kv2.z, acc[r].z); acc[r].w = fmaf(qv.z, kv2.w, acc[r].w);
        acc[r].x = fmaf(qv.w, kv3.x, acc[r].x); acc[r].y = fmaf(qv.w, kv3.y, acc[r].y);
        acc[r].z = fmaf(qv.w, kv3.z, acc[r].z); acc[r].w = fmaf(qv.w, kv3.w, acc[r].w);
      }
    }

    const float IS = 11.313708498984761f;  // sqrt(2*dh): reference DIVIDES by 1/sqrt(2dh)
    int k0 = 4 * t;
    #pragma unroll
    for (int r = 0; r < QR; ++r) {
      int rel = k0 - (q0 + r) + ML;   // in [1, 2047]
      float4 o = {acc[r].x * IS + bt[(rel + 0) * NH + h],
                  acc[r].y * IS + bt[(rel + 1) * NH + h],
                  acc[r].z * IS + bt[(rel + 2) * NH + h],
                  acc[r].w * IS + bt[(rel + 3) * NH + h]};
      *(float4*)&Lg[r][k0] = o;
    }
  }
  __syncthreads();

  // ---- phase 2: softmax per row (4 waves x 2 rows) ----
  {
    int wv = t >> 6, lane = t & 63;
    #pragma unroll
    for (int rr = 0; rr < QR / 4; ++rr) {
      int r = wv * (QR / 4) + rr;
      float m = -INFINITY;
      for (int k = lane; k < SB; k += 64) m = fmaxf(m, Lg[r][k]);
      #pragma unroll
      for (int o = 32; o > 0; o >>= 1) m = fmaxf(m, __shfl_xor(m, o, 64));
      float ss = 0.f;
      for (int k = lane; k < SB; k += 64) {
        float e = expf(Lg[r][k] - m);
        Lg[r][k] = e;
        ss += e;
      }
      #pragma unroll
      for (int o = 32; o > 0; o >>= 1) ss += __shfl_xor(ss, o, 64);
      if (lane == 0) inv_sum[r] = 1.0f / ss;
    }
  }
  __syncthreads();

  // ---- phase 3: PV. thread -> (r = t>>5, dp = t&31), float2 over d ----
  {
    int r = t >> 5, dp = t & 31;
    const float* V = tok + (size_t)(b * SB) * (3 * DM) + 2 * DM + h * DH + dp * 2;
    float2 o = {0.f, 0.f};
    for (int k = 0; k < SB; ++k) {
      float p = Lg[r][k];
      float2 vv = *(const float2*)(V + (size_t)k * (3 * DM));
      o.x = fmaf(p, vv.x, o.x);
      o.y = fmaf(p, vv.y, o.y);
    }
    float is = inv_sum[r];
    o.x *= is; o.y *= is;
    *(float2*)(out + (size_t)(b * SB + q0 + r) * DM + h * DH + dp * 2) = o;
  }
}

extern "C" void kernel_launch(void* const* d_in, const int* in_sizes, int n_in,
                              void* d_out, int out_size, void* d_ws, size_t ws_size,
                              hipStream_t stream) {
  const float* x     = (const float*)d_in[0];
  const float* gamma = (const float*)d_in[1];
  const float* beta  = (const float*)d_in[2];
  const float* w_pos = (const float*)d_in[3];
  const float* w_tok = (const float*)d_in[4];
  const float* bt    = (const float*)d_in[5];
  float* out = (float*)d_out;
  float* ws  = (float*)d_ws;

  // Workspace layout (19M floats = 76 MB, same footprint as round 1):
  //   [0,   1M)  pe   -> dead after pos GEMM -> reused as Kp [H,64,S]
  //   [1M,  3M)  pos  (pos_k | pos_q), live through attn (pos_q in Qc load)
  //   [3M,  7M)  xn   -> dead after tok GEMM -> reused as Kt [B,H,64,S]
  //   [7M, 19M)  tok  (k | q | v), live through attn
  float* pe  = ws;
  float* pos = ws + (1u << 20);
  float* xn  = ws + 3u * (1u << 20);
  float* tok = ws + 7u * (1u << 20);
  float* Kp  = pe;   // overlay
  float* Kt  = xn;   // overlay

  pe_kernel<<<SB, 256, 0, stream>>>(pe);
  ln_kernel<<<BB * SB, 256, 0, stream>>>(x, gamma, beta, xn);
  // pos = pe @ w_pos^T : [1024, 2048]
  gemm_nt<<<dim3((2 * DM) / BN, SB / BM), 256, 0, stream>>>(pe, w_pos, pos, SB, 2 * DM, DM);
  // tok = xn @ w_tok^T : [4096, 3072]
  gemm_nt<<<dim3((3 * DM) / BN, (BB * SB) / BM), 256, 0, stream>>>(xn, w_tok, tok, BB * SB, 3 * DM, DM);
  // pack K (tok_k per batch + pos_k) into d-major, s-contiguous layout
  pack_k_kernel<<<dim3(SB / 64, NH, BB + 1), 256, 0, stream>>>(tok, pos, Kt, Kp);
  attn_kernel<<<BB * NH * (SB / QR), 256, 0, stream>>>(tok, pos, Kt, Kp, bt, out);
}

// Round 3
// 795.717 us; speedup vs baseline: 2.4724x; 2.1107x over previous
//
#include <hip/hip_runtime.h>
#include <math.h>

#define SB 1024   // seq len
#define DM 1024   // d_model
#define BB 4      // batch
#define NH 16     // heads
#define DH 64     // head dim
#define ML 1024   // MAX_LEN

typedef __attribute__((ext_vector_type(8))) short short8;
typedef __attribute__((ext_vector_type(4))) short short4v;
typedef __attribute__((ext_vector_type(4))) float f32x4;

__device__ __forceinline__ unsigned short f2bf(float x) {
  unsigned u = __float_as_uint(x);
  u += 0x7fffu + ((u >> 16) & 1u);
  return (unsigned short)(u >> 16);
}
__device__ __forceinline__ float bf2f(unsigned short h) {
  return __uint_as_float((unsigned)h << 16);
}

// ---------------- sinusoidal positional encoding ----------------
__global__ void pe_kernel(float* __restrict__ pe) {
  int p = blockIdx.x;
  for (int i = threadIdx.x; i < DM / 2; i += 256) {
    float div = expf((float)(2 * i) * (-9.210340371976184f / (float)DM));
    float ang = (float)p * div;
    pe[(size_t)p * DM + 2 * i]     = sinf(ang);
    pe[(size_t)p * DM + 2 * i + 1] = cosf(ang);
  }
}

// ---------------- layernorm ----------------
__device__ __forceinline__ float block_sum256(float s, float* red) {
  #pragma unroll
  for (int o = 32; o > 0; o >>= 1) s += __shfl_down(s, o, 64);
  int t = threadIdx.x;
  if ((t & 63) == 0) red[t >> 6] = s;
  __syncthreads();
  float tot = red[0] + red[1] + red[2] + red[3];
  __syncthreads();
  return tot;
}

__global__ __launch_bounds__(256) void ln_kernel(const float* __restrict__ x,
    const float* __restrict__ gamma, const float* __restrict__ beta,
    float* __restrict__ xn) {
  __shared__ float red[4];
  int row = blockIdx.x;
  const float4* xr = (const float4*)(x + (size_t)row * DM);
  int t = threadIdx.x;
  float4 v = xr[t];
  float mu = block_sum256(v.x + v.y + v.z + v.w, red) * (1.0f / DM);
  float4 d = {v.x - mu, v.y - mu, v.z - mu, v.w - mu};
  float var = block_sum256(d.x*d.x + d.y*d.y + d.z*d.z + d.w*d.w, red) * (1.0f / DM);
  float rstd = rsqrtf(var + 1e-5f);
  float4 g  = ((const float4*)gamma)[t];
  float4 bb = ((const float4*)beta)[t];
  float4 o = {d.x * rstd * g.x + bb.x, d.y * rstd * g.y + bb.y,
              d.z * rstd * g.z + bb.z, d.w * rstd * g.w + bb.w};
  ((float4*)(xn + (size_t)row * DM))[t] = o;
}

// ---------------- fp32 GEMM: C[M,N] = A[M,K] * W[N,K]^T ----------------
#define BM 128
#define BN 128
#define BK 16

__global__ __launch_bounds__(256) void gemm_nt(const float* __restrict__ A,
    const float* __restrict__ W, float* __restrict__ C,
    int M, int N, int K) {
  __shared__ float As[BK][BM + 4];
  __shared__ float Ws[BK][BN + 4];
  int m0 = blockIdx.y * BM;
  int n0 = blockIdx.x * BN;
  int t = threadIdx.x;
  int tx = t & 15, ty = t >> 4;
  float acc[8][8];
  #pragma unroll
  for (int i = 0; i < 8; ++i)
    #pragma unroll
    for (int j = 0; j < 8; ++j) acc[i][j] = 0.f;

  for (int kt = 0; kt < K; kt += BK) {
    #pragma unroll
    for (int l = 0; l < 2; ++l) {
      int idx = t + l * 256;
      int r = idx >> 2;
      int kc = (idx & 3) << 2;
      float4 av = *(const float4*)(A + (size_t)(m0 + r) * K + kt + kc);
      As[kc + 0][r] = av.x; As[kc + 1][r] = av.y;
      As[kc + 2][r] = av.z; As[kc + 3][r] = av.w;
      float4 wv = *(const float4*)(W + (size_t)(n0 + r) * K + kt + kc);
      Ws[kc + 0][r] = wv.x; Ws[kc + 1][r] = wv.y;
      Ws[kc + 2][r] = wv.z; Ws[kc + 3][r] = wv.w;
    }
    __syncthreads();
    #pragma unroll
    for (int kk = 0; kk < BK; ++kk) {
      float4 a0 = *(const float4*)&As[kk][ty * 8];
      float4 a1 = *(const float4*)&As[kk][ty * 8 + 4];
      float4 w0 = *(const float4*)&Ws[kk][tx * 8];
      float4 w1 = *(const float4*)&Ws[kk][tx * 8 + 4];
      float a_[8] = {a0.x, a0.y, a0.z, a0.w, a1.x, a1.y, a1.z, a1.w};
      float w_[8] = {w0.x, w0.y, w0.z, w0.w, w1.x, w1.y, w1.z, w1.w};
      #pragma unroll
      for (int i = 0; i < 8; ++i)
        #pragma unroll
        for (int j = 0; j < 8; ++j)
          acc[i][j] = fmaf(a_[i], w_[j], acc[i][j]);
    }
    __syncthreads();
  }
  #pragma unroll
  for (int i = 0; i < 8; ++i) {
    float4 o0 = {acc[i][0], acc[i][1], acc[i][2], acc[i][3]};
    float4 o1 = {acc[i][4], acc[i][5], acc[i][6], acc[i][7]};
    float* cp = C + (size_t)(m0 + ty * 8 + i) * N + n0 + tx * 8;
    *(float4*)cp = o0;
    *(float4*)(cp + 4) = o1;
  }
}

// ---------------- pack V transposed to bf16: Vt[b][h][d][s] ----------------
__global__ __launch_bounds__(256) void pack_vt_kernel(
    const float* __restrict__ tok, unsigned short* __restrict__ Vt) {
  __shared__ float Ts[64][65];
  int st = blockIdx.x;   // s-tile (16)
  int h  = blockIdx.y;
  int b  = blockIdx.z;
  int t = threadIdx.x;
  int s0 = st * 64;
  #pragma unroll
  for (int it = 0; it < 4; ++it) {
    int s = it * 16 + (t >> 4);
    int d4 = t & 15;
    float4 v = *(const float4*)(tok + (size_t)(b * SB + s0 + s) * (3 * DM)
                                + 2 * DM + h * DH + d4 * 4);
    Ts[s][d4 * 4 + 0] = v.x; Ts[s][d4 * 4 + 1] = v.y;
    Ts[s][d4 * 4 + 2] = v.z; Ts[s][d4 * 4 + 3] = v.w;
  }
  __syncthreads();
  unsigned short* outp = Vt + (size_t)((b * NH + h) * DH) * SB;
  #pragma unroll
  for (int it = 0; it < 4; ++it) {
    int d = it * 16 + (t >> 4);
    int s4 = t & 15;
    short4v o = {(short)f2bf(Ts[s4 * 4 + 0][d]), (short)f2bf(Ts[s4 * 4 + 1][d]),
                 (short)f2bf(Ts[s4 * 4 + 2][d]), (short)f2bf(Ts[s4 * 4 + 3][d])};
    *(short4v*)(outp + (size_t)d * SB + s0 + s4 * 4) = o;
  }
}

// ---------------- bias table transpose: btT[h][rel] ----------------
__global__ __launch_bounds__(256) void btt_kernel(
    const float* __restrict__ bt, float* __restrict__ btT) {
  int h = blockIdx.x;
  for (int r = threadIdx.x; r < 2 * ML; r += 256)
    btT[(size_t)h * (2 * ML) + r] = bt[(size_t)r * NH + h];
}

// ---------------- MFMA flash attention ----------------
// Block = (b, h, 64 q-rows); 4 waves x 16 q each. K-loop over 64-k tiles:
// stage K fp32 -> split-bf16 LDS; S = Qhi*Khi + Qlo*Khi + Qhi*Klo (fp32 acc);
// online softmax in C-layout; P -> LDS roundtrip to A-layout; PV with bf16 Vt.
#define KT 64

__global__ __launch_bounds__(256) void attn_mfma(
    const float* __restrict__ tok,   // [B,S,3D]: k | q | v  (fp32)
    const float* __restrict__ pos,   // [S,2D]: pos_k | pos_q (fp32)
    const unsigned short* __restrict__ Vt,  // [B,H,64,S] bf16
    const float* __restrict__ btT,   // [H, 2*ML]
    float* __restrict__ out) {       // [B,S,D]
  __shared__ unsigned short Khi[KT * 136];  // row stride 272B: 16B-aligned, uniform banks
  __shared__ unsigned short Klo[KT * 136];
  __shared__ unsigned short Pb[4][16 * 72]; // per-wave P, row stride 144B

  int bid = blockIdx.x;
  int qt = bid & 15;
  int h  = (bid >> 4) & 15;
  int b  = bid >> 8;
  int q0 = qt * 64;
  int t = threadIdx.x;
  int wv = t >> 6;
  int lane = t & 63;
  int g = lane >> 4;      // quad
  int r16 = lane & 15;

  // ---- Q fragments: 16 q-rows/wave, scale sqrt(2*dh) folded in, split hi/lo
  const float IS = 11.313708498984761f;   // reference divides by 1/sqrt(2*dh)
  int qrow = q0 + wv * 16 + r16;          // A-layout: m = lane&15
  short8 qhi[4], qlo[4];
  #pragma unroll
  for (int c = 0; c < 4; ++c) {
    const float* src = (c < 2)
      ? tok + (size_t)(b * SB + qrow) * (3 * DM) + DM + h * DH + c * 32 + g * 8
      : pos + (size_t)qrow * (2 * DM) + DM + h * DH + (c - 2) * 32 + g * 8;
    float4 a0 = *(const float4*)src;
    float4 a1 = *(const float4*)(src + 4);
    float v[8] = {a0.x, a0.y, a0.z, a0.w, a1.x, a1.y, a1.z, a1.w};
    #pragma unroll
    for (int j = 0; j < 8; ++j) {
      float s = v[j] * IS;
      unsigned short hi = f2bf(s);
      qhi[c][j] = (short)hi;
      qlo[c][j] = (short)f2bf(s - bf2f(hi));
    }
  }

  f32x4 O[4];
  #pragma unroll
  for (int dt = 0; dt < 4; ++dt) O[dt] = (f32x4){0.f, 0.f, 0.f, 0.f};
  float m_run[4] = {-3e38f, -3e38f, -3e38f, -3e38f};
  float l_run[4] = {0.f, 0.f, 0.f, 0.f};

  const float* bts = btT + (size_t)h * (2 * ML);
  const unsigned short* Vb = Vt + (size_t)((b * NH + h) * DH) * SB;
  int qbase = q0 + wv * 16 + g * 4;       // C-layout row base: row = g*4+reg

  for (int kt = 0; kt < SB / KT; ++kt) {
    int k0 = kt * KT;
    __syncthreads();
    // ---- stage K-tile (64k x 128 dims fp32) -> split bf16 hi/lo in LDS
    #pragma unroll
    for (int i = 0; i < 8; ++i) {
      int idx = i * 256 + t;
      int kr = idx >> 5;            // 0..63
      int c4 = idx & 31;            // float4 index over 128 dims
      const float* src = (c4 < 16)
        ? tok + (size_t)(b * SB + k0 + kr) * (3 * DM) + h * DH + c4 * 4
        : pos + (size_t)(k0 + kr) * (2 * DM) + h * DH + (c4 - 16) * 4;
      float4 v = *(const float4*)src;
      float vv[4] = {v.x, v.y, v.z, v.w};
      short4v hi4, lo4;
      #pragma unroll
      for (int j = 0; j < 4; ++j) {
        unsigned short hi = f2bf(vv[j]);
        hi4[j] = (short)hi;
        lo4[j] = (short)f2bf(vv[j] - bf2f(hi));
      }
      *(short4v*)&Khi[kr * 136 + c4 * 4] = hi4;
      *(short4v*)&Klo[kr * 136 + c4 * 4] = lo4;
    }
    __syncthreads();

    // ---- QK^T: 4 n-tiles x (4 dim-chunks x 3 split combos) MFMA
    f32x4 S[4];
    #pragma unroll
    for (int nt = 0; nt < 4; ++nt) {
      f32x4 acc = (f32x4){0.f, 0.f, 0.f, 0.f};
      int row = nt * 16 + r16;      // B-layout: n = lane&15
      #pragma unroll
      for (int c = 0; c < 4; ++c) {
        short8 bhi = *(const short8*)&Khi[row * 136 + c * 32 + g * 8];
        short8 blo = *(const short8*)&Klo[row * 136 + c * 32 + g * 8];
        acc = __builtin_amdgcn_mfma_f32_16x16x32_bf16(qhi[c], bhi, acc, 0, 0, 0);
        acc = __builtin_amdgcn_mfma_f32_16x16x32_bf16(qlo[c], bhi, acc, 0, 0, 0);
        acc = __builtin_amdgcn_mfma_f32_16x16x32_bf16(qhi[c], blo, acc, 0, 0, 0);
      }
      S[nt] = acc;
    }

    // ---- rel-pos bias: C-layout col = k0+nt*16+r16, row = qbase+reg
    #pragma unroll
    for (int nt = 0; nt < 4; ++nt) {
      int kk = k0 + nt * 16 + r16;
      #pragma unroll
      for (int reg = 0; reg < 4; ++reg)
        S[nt][reg] += bts[ML + kk - (qbase + reg)];
    }

    // ---- online softmax (rows spread over 16-lane groups)
    float tm[4], al[4], ts[4];
    #pragma unroll
    for (int reg = 0; reg < 4; ++reg)
      tm[reg] = fmaxf(fmaxf(S[0][reg], S[1][reg]), fmaxf(S[2][reg], S[3][reg]));
    #pragma unroll
    for (int off = 1; off < 16; off <<= 1)
      #pragma unroll
      for (int reg = 0; reg < 4; ++reg)
        tm[reg] = fmaxf(tm[reg], __shfl_xor(tm[reg], off, 64));
    #pragma unroll
    for (int reg = 0; reg < 4; ++reg) {
      float mn = fmaxf(m_run[reg], tm[reg]);
      al[reg] = __expf(m_run[reg] - mn);
      m_run[reg] = mn;
      ts[reg] = 0.f;
    }
    #pragma unroll
    for (int nt = 0; nt < 4; ++nt)
      #pragma unroll
      for (int reg = 0; reg < 4; ++reg) {
        float p = __expf(S[nt][reg] - m_run[reg]);
        S[nt][reg] = p;
        ts[reg] += p;
      }
    #pragma unroll
    for (int off = 1; off < 16; off <<= 1)
      #pragma unroll
      for (int reg = 0; reg < 4; ++reg)
        ts[reg] += __shfl_xor(ts[reg], off, 64);
    #pragma unroll
    for (int reg = 0; reg < 4; ++reg)
      l_run[reg] = l_run[reg] * al[reg] + ts[reg];
    #pragma unroll
    for (int dt = 0; dt < 4; ++dt)
      #pragma unroll
      for (int reg = 0; reg < 4; ++reg)
        O[dt][reg] *= al[reg];

    // ---- P (C-layout) -> per-wave LDS -> A-layout frags
    unsigned short* pb = Pb[wv];
    #pragma unroll
    for (int nt = 0; nt < 4; ++nt)
      #pragma unroll
      for (int reg = 0; reg < 4; ++reg)
        pb[(g * 4 + reg) * 72 + nt * 16 + r16] = f2bf(S[nt][reg]);

    // ---- PV: 2 k-chunks of 32; V B-frags straight from global bf16 Vt
    #pragma unroll
    for (int kc = 0; kc < 2; ++kc) {
      short8 pa = *(const short8*)&pb[r16 * 72 + kc * 32 + g * 8];
      #pragma unroll
      for (int dt = 0; dt < 4; ++dt) {
        short8 bv = *(const short8*)&Vb[(size_t)(dt * 16 + r16) * SB + k0 + kc * 32 + g * 8];
        O[dt] = __builtin_amdgcn_mfma_f32_16x16x32_bf16(pa, bv, O[dt], 0, 0, 0);
      }
    }
  }

  // ---- epilogue: O /= l, write fp32
  #pragma unroll
  for (int reg = 0; reg < 4; ++reg) l_run[reg] = 1.0f / l_run[reg];
  #pragma unroll
  for (int dt = 0; dt < 4; ++dt)
    #pragma unroll
    for (int reg = 0; reg < 4; ++reg)
      out[(size_t)(b * SB + qbase + reg) * DM + h * DH + dt * 16 + r16] =
          O[dt][reg] * l_run[reg];
}

extern "C" void kernel_launch(void* const* d_in, const int* in_sizes, int n_in,
                              void* d_out, int out_size, void* d_ws, size_t ws_size,
                              hipStream_t stream) {
  const float* x     = (const float*)d_in[0];
  const float* gamma = (const float*)d_in[1];
  const float* beta  = (const float*)d_in[2];
  const float* w_pos = (const float*)d_in[3];
  const float* w_tok = (const float*)d_in[4];
  const float* bt    = (const float*)d_in[5];
  float* out = (float*)d_out;
  float* ws  = (float*)d_ws;

  // Workspace (76 MB):
  //   [0,  1M) floats: pe           (dead after pos GEMM)
  //   [1M, 3M) floats: pos          (live through attn)
  //   [3M, 7M) floats: xn           (dead after tok GEMM) -> overlaid:
  //        [3M, 5M) floats = Vt (4M bf16 ushorts, 8 MB)
  //        [5M, 5M+32K)   = btT (16 x 2048 f32)
  //   [7M,19M) floats: tok          (live through attn)
  float* pe  = ws;
  float* pos = ws + (1u << 20);
  float* xn  = ws + 3u * (1u << 20);
  float* tok = ws + 7u * (1u << 20);
  unsigned short* Vt = (unsigned short*)(ws + 3u * (1u << 20));
  float* btT = ws + 5u * (1u << 20);

  pe_kernel<<<SB, 256, 0, stream>>>(pe);
  ln_kernel<<<BB * SB, 256, 0, stream>>>(x, gamma, beta, xn);
  gemm_nt<<<dim3((2 * DM) / BN, SB / BM), 256, 0, stream>>>(pe, w_pos, pos, SB, 2 * DM, DM);
  gemm_nt<<<dim3((3 * DM) / BN, (BB * SB) / BM), 256, 0, stream>>>(xn, w_tok, tok, BB * SB, 3 * DM, DM);
  pack_vt_kernel<<<dim3(SB / 64, NH, BB), 256, 0, stream>>>(tok, Vt);
  btt_kernel<<<NH, 256, 0, stream>>>(bt, btT);
  attn_mfma<<<BB * NH * (SB / 64), 256, 0, stream>>>(tok, pos, Vt, btT, out);
}

// Round 4
// 436.334 us; speedup vs baseline: 4.5088x; 1.8236x over previous
//
#include <hip/hip_runtime.h>
#include <math.h>

#define SB 1024   // seq len
#define DM 1024   // d_model
#define BB 4      // batch
#define NH 16     // heads
#define DH 64     // head dim
#define ML 1024   // MAX_LEN

typedef __attribute__((ext_vector_type(8))) short short8;
typedef __attribute__((ext_vector_type(8))) _Float16 half8;
typedef __attribute__((ext_vector_type(4))) float f32x4;
typedef unsigned short u16;

__device__ __forceinline__ u16 f2bf(float x) {
  unsigned u = __float_as_uint(x);
  u += 0x7fffu + ((u >> 16) & 1u);
  return (u16)(u >> 16);
}
__device__ __forceinline__ float bf2f(u16 h) { return __uint_as_float((unsigned)h << 16); }

// async global->LDS, 16B per lane; lds base must be wave-uniform (HW adds lane*16)
__device__ __forceinline__ void async16(void* lds, const void* g) {
  __builtin_amdgcn_global_load_lds(
      (const __attribute__((address_space(1))) unsigned*)g,
      (__attribute__((address_space(3))) unsigned*)lds, 16, 0, 0);
}

// ---------------- sinusoidal positional encoding ----------------
__global__ void pe_kernel(float* __restrict__ pe) {
  int p = blockIdx.x;
  for (int i = threadIdx.x; i < DM / 2; i += 256) {
    float div = expf((float)(2 * i) * (-9.210340371976184f / (float)DM));
    float ang = (float)p * div;
    pe[(size_t)p * DM + 2 * i]     = sinf(ang);
    pe[(size_t)p * DM + 2 * i + 1] = cosf(ang);
  }
}

// ---------------- layernorm (fp32 out) ----------------
__device__ __forceinline__ float block_sum256(float s, float* red) {
  #pragma unroll
  for (int o = 32; o > 0; o >>= 1) s += __shfl_down(s, o, 64);
  int t = threadIdx.x;
  if ((t & 63) == 0) red[t >> 6] = s;
  __syncthreads();
  float tot = red[0] + red[1] + red[2] + red[3];
  __syncthreads();
  return tot;
}

__global__ __launch_bounds__(256) void ln_kernel(const float* __restrict__ x,
    const float* __restrict__ gamma, const float* __restrict__ beta,
    float* __restrict__ xn) {
  __shared__ float red[4];
  int row = blockIdx.x;
  const float4* xr = (const float4*)(x + (size_t)row * DM);
  int t = threadIdx.x;
  float4 v = xr[t];
  float mu = block_sum256(v.x + v.y + v.z + v.w, red) * (1.0f / DM);
  float4 d = {v.x - mu, v.y - mu, v.z - mu, v.w - mu};
  float var = block_sum256(d.x*d.x + d.y*d.y + d.z*d.z + d.w*d.w, red) * (1.0f / DM);
  float rstd = rsqrtf(var + 1e-5f);
  float4 g  = ((const float4*)gamma)[t];
  float4 bb = ((const float4*)beta)[t];
  float4 o = {d.x * rstd * g.x + bb.x, d.y * rstd * g.y + bb.y,
              d.z * rstd * g.z + bb.z, d.w * rstd * g.w + bb.w};
  ((float4*)(xn + (size_t)row * DM))[t] = o;
}

// ---------------- pack fp32 [R][1024] -> split-fp16 frag-chunk planes ----------------
// plane layout: [rt=R/16][kt=32][lane=64][j=8], element = src[rt*16 + (lane&15)][kt*32 + (lane>>4)*8 + j]
__global__ __launch_bounds__(256) void pack16(const float* __restrict__ src,
    _Float16* __restrict__ dH, _Float16* __restrict__ dL, float scale) {
  int rt = blockIdx.x;
  int t = threadIdx.x;
  int r16 = t >> 4, ks = t & 15;
  const float* sp = src + (size_t)(rt * 16 + r16) * 1024 + ks * 64;
  float v[64];
  #pragma unroll
  for (int i = 0; i < 16; ++i) {
    float4 f = *(const float4*)(sp + i * 4);
    v[i*4+0] = f.x; v[i*4+1] = f.y; v[i*4+2] = f.z; v[i*4+3] = f.w;
  }
  #pragma unroll
  for (int hf = 0; hf < 2; ++hf) {
    int kt = ks * 2 + hf;
    #pragma unroll
    for (int gg = 0; gg < 4; ++gg) {
      half8 hv, lv;
      #pragma unroll
      for (int j = 0; j < 8; ++j) {
        float x = v[hf * 32 + gg * 8 + j] * scale;
        _Float16 h = (_Float16)x;
        hv[j] = h;
        lv[j] = (_Float16)(x - (float)h);
      }
      size_t off = ((size_t)(rt * 32 + kt) * 64 + r16 + gg * 16) * 8;
      *(half8*)(dH + off) = hv;
      *(half8*)(dL + off) = lv;
    }
  }
}

// ---------------- split-fp16 MFMA GEMM ----------------
// C[M,N] = (AH+AL)[M,K] * (BH+BL)[N,K]^T, 3 passes (hh, lh, hl), fp32 accum.
// Output: per-1024-col band b: c = acc*scale_b -> bf16 hi (+ lo if ptr != null), ld = 1024.
#define GBM 128
#define GBN 256

__global__ __launch_bounds__(256, 2) void gemm16(
    const _Float16* __restrict__ AH, const _Float16* __restrict__ AL,
    const _Float16* __restrict__ BH, const _Float16* __restrict__ BL,
    u16* __restrict__ o0H, u16* __restrict__ o0L, float s0,
    u16* __restrict__ o1H, u16* __restrict__ o1L, float s1,
    u16* __restrict__ o2H, u16* __restrict__ o2L, float s2) {
  __shared__ _Float16 L[32 * 512];   // 32 chunks x 1KB: A(16: mt*2+pl), Bhi(16: 16+nt)
  int t = threadIdx.x;
  int wv = t >> 6, lane = t & 63;
  int wm = wv >> 1, wn = wv & 1;
  int r16 = lane & 15, g = lane >> 4;
  int m0 = blockIdx.y * GBM;
  int n0 = blockIdx.x * GBN;
  int mt0 = m0 >> 4, nt0 = n0 >> 4;

  f32x4 acc[4][8];
  #pragma unroll
  for (int i = 0; i < 4; ++i)
    #pragma unroll
    for (int j = 0; j < 8; ++j) acc[i][j] = (f32x4){0.f, 0.f, 0.f, 0.f};

  for (int kt = 0; kt < 32; ++kt) {
    __syncthreads();
    #pragma unroll
    for (int rd = 0; rd < 8; ++rd) {
      int ci = rd * 4 + wv;
      const _Float16* src;
      if (ci < 16) {
        int mt = ci >> 1, pl = ci & 1;
        const _Float16* P = pl ? AL : AH;
        src = P + ((size_t)((mt0 + mt) * 32 + kt) * 64 + lane) * 8;
      } else {
        int nt = ci - 16;
        src = BH + ((size_t)((nt0 + nt) * 32 + kt) * 64 + lane) * 8;
      }
      async16(&L[ci * 512], src);
    }
    // Blo fragments straight from global (frag-linear, coalesced, L2-hot)
    half8 blo[8];
    #pragma unroll
    for (int j = 0; j < 8; ++j) {
      int ntg = nt0 + wn * 8 + j;
      blo[j] = *(const half8*)(BL + ((size_t)(ntg * 32 + kt) * 64 + lane) * 8);
    }
    __syncthreads();

    half8 ah[4], al[4];
    #pragma unroll
    for (int i = 0; i < 4; ++i) {
      ah[i] = *(const half8*)&L[(((wm * 4 + i) * 2 + 0) * 512) + lane * 8];
      al[i] = *(const half8*)&L[(((wm * 4 + i) * 2 + 1) * 512) + lane * 8];
    }
    #pragma unroll
    for (int j = 0; j < 8; ++j) {
      half8 bh = *(const half8*)&L[((16 + wn * 8 + j) * 512) + lane * 8];
      #pragma unroll
      for (int i = 0; i < 4; ++i) {
        acc[i][j] = __builtin_amdgcn_mfma_f32_16x16x32_f16(ah[i], bh, acc[i][j], 0, 0, 0);
        acc[i][j] = __builtin_amdgcn_mfma_f32_16x16x32_f16(al[i], bh, acc[i][j], 0, 0, 0);
        acc[i][j] = __builtin_amdgcn_mfma_f32_16x16x32_f16(ah[i], blo[j], acc[i][j], 0, 0, 0);
      }
    }
  }

  #pragma unroll
  for (int i = 0; i < 4; ++i)
    #pragma unroll
    for (int j = 0; j < 8; ++j) {
      int col = n0 + wn * 128 + j * 16 + r16;
      int band = col >> 10, lc = col & 1023;
      float sc = band == 0 ? s0 : band == 1 ? s1 : s2;
      u16* oh = band == 0 ? o0H : band == 1 ? o1H : o2H;
      u16* ol = band == 0 ? o0L : band == 1 ? o1L : o2L;
      #pragma unroll
      for (int reg = 0; reg < 4; ++reg) {
        int row = m0 + wm * 64 + i * 16 + g * 4 + reg;
        float c = acc[i][j][reg] * sc;
        u16 hi = f2bf(c);
        oh[(size_t)row * 1024 + lc] = hi;
        if (ol) ol[(size_t)row * 1024 + lc] = f2bf(c - bf2f(hi));
      }
    }
}

// ---------------- pack V (bf16 [B*S][1024] cols h*64+d) -> frag chunks ----------------
// Vf[bh][kc=32][dt=4][lane=64][j=8]: element = V[s = kc*32 + (lane>>4)*8 + j][d = dt*16 + (lane&15)]
__global__ __launch_bounds__(256) void pack_v(const u16* __restrict__ VHg,
    u16* __restrict__ Vf) {
  int sg = blockIdx.x;   // 16 groups of 64 s
  int h = blockIdx.y, b = blockIdx.z;
  int bh = b * NH + h;
  int t = threadIdx.x;
  int r = t >> 2, q = t & 3;
  int s = sg * 64 + r;
  int kc = s >> 5, g = (s >> 3) & 3, j = s & 7;
  const u16* sp = VHg + (size_t)(b * SB + s) * 1024 + h * 64 + q * 16;
  u16 vv[16];
  *(short8*)&vv[0] = *(const short8*)sp;
  *(short8*)&vv[8] = *(const short8*)(sp + 8);
  u16* dp = Vf + ((size_t)(bh * 32 + kc) * 4 + q) * 512 + g * 128 + j;
  #pragma unroll
  for (int e = 0; e < 16; ++e) dp[e * 8] = vv[e];
}

// ---------------- bias table transpose: btT[h][rel] ----------------
__global__ __launch_bounds__(256) void btt_kernel(
    const float* __restrict__ bt, float* __restrict__ btT) {
  int h = blockIdx.x;
  for (int r = threadIdx.x; r < 2 * ML; r += 256)
    btT[(size_t)h * (2 * ML) + r] = bt[(size_t)r * NH + h];
}

// ---------------- MFMA flash attention v2 ----------------
// Q (pre-scaled by IS) and K are split-bf16 planes from gemm16; staging is pure
// global_load_lds into frag-linear LDS; V from pre-shuffled frag chunks.
#define KT 64

__global__ __launch_bounds__(256) void attn_mfma2(
    const u16* __restrict__ KHg, const u16* __restrict__ KLg,   // [B*S][1024]
    const u16* __restrict__ pKH, const u16* __restrict__ pKL,   // [S][1024]
    const u16* __restrict__ QHg, const u16* __restrict__ QLg,   // [B*S][1024] (x IS)
    const u16* __restrict__ pQH, const u16* __restrict__ pQL,   // [S][1024] (x IS)
    const u16* __restrict__ Vf,                                  // frag chunks
    const float* __restrict__ btT, float* __restrict__ out) {
  __shared__ u16 Kl[32 * 512];       // 32 chunks (nt*8 + c*2 + pl) x 1KB
  __shared__ u16 Pb[4][16 * 72];
  int bid = blockIdx.x;
  int qt = bid & 15;
  int h  = (bid >> 4) & 15;
  int b  = bid >> 8;
  int q0 = qt * 64;
  int t = threadIdx.x;
  int wv = t >> 6, lane = t & 63;
  int g = lane >> 4, r16 = lane & 15;
  int bh = b * NH + h;

  // ---- Q fragments (A-layout), hi/lo straight from split planes
  int qrow = q0 + wv * 16 + r16;
  short8 qhi[4], qlo[4];
  #pragma unroll
  for (int c = 0; c < 4; ++c) {
    if (c < 2) {
      size_t off = (size_t)(b * SB + qrow) * 1024 + h * DH + c * 32 + g * 8;
      qhi[c] = *(const short8*)(QHg + off);
      qlo[c] = *(const short8*)(QLg + off);
    } else {
      size_t off = (size_t)qrow * 1024 + h * DH + (c - 2) * 32 + g * 8;
      qhi[c] = *(const short8*)(pQH + off);
      qlo[c] = *(const short8*)(pQL + off);
    }
  }

  f32x4 O[4];
  #pragma unroll
  for (int dt = 0; dt < 4; ++dt) O[dt] = (f32x4){0.f, 0.f, 0.f, 0.f};
  float m_run[4] = {-3e38f, -3e38f, -3e38f, -3e38f};
  float l_run[4] = {0.f, 0.f, 0.f, 0.f};

  const float* bts = btT + (size_t)h * (2 * ML);
  int qbase = q0 + wv * 16 + g * 4;

  for (int kt = 0; kt < SB / KT; ++kt) {
    int k0 = kt * KT;
    __syncthreads();
    // ---- stage K-tile: 32 chunks via global_load_lds (lane -> (s&15) + (dgrp)*16)
    #pragma unroll
    for (int i = 0; i < 8; ++i) {
      int pl = i >> 2, c = i & 3;
      int s = k0 + wv * 16 + (lane & 15);
      const u16* src = (c < 2)
        ? (pl ? KLg : KHg) + (size_t)(b * SB + s) * 1024 + h * DH + c * 32 + (lane >> 4) * 8
        : (pl ? pKL : pKH) + (size_t)s * 1024 + h * DH + (c - 2) * 32 + (lane >> 4) * 8;
      async16(&Kl[(wv * 8 + c * 2 + pl) * 512], src);
    }
    __syncthreads();

    // ---- QK^T: S[q][k] = (Qhi+Qlo).(Khi+Klo), 3-term
    f32x4 S[4];
    #pragma unroll
    for (int nt = 0; nt < 4; ++nt) {
      f32x4 acc = (f32x4){0.f, 0.f, 0.f, 0.f};
      #pragma unroll
      for (int c = 0; c < 4; ++c) {
        short8 bhi = *(const short8*)&Kl[((nt * 8 + c * 2 + 0) * 512) + lane * 8];
        short8 blo = *(const short8*)&Kl[((nt * 8 + c * 2 + 1) * 512) + lane * 8];
        acc = __builtin_amdgcn_mfma_f32_16x16x32_bf16(qhi[c], bhi, acc, 0, 0, 0);
        acc = __builtin_amdgcn_mfma_f32_16x16x32_bf16(qlo[c], bhi, acc, 0, 0, 0);
        acc = __builtin_amdgcn_mfma_f32_16x16x32_bf16(qhi[c], blo, acc, 0, 0, 0);
      }
      S[nt] = acc;
    }

    // ---- rel-pos bias
    #pragma unroll
    for (int nt = 0; nt < 4; ++nt) {
      int kk = k0 + nt * 16 + r16;
      #pragma unroll
      for (int reg = 0; reg < 4; ++reg)
        S[nt][reg] += bts[ML + kk - (qbase + reg)];
    }

    // ---- online softmax
    float tm[4], al[4], ts[4];
    #pragma unroll
    for (int reg = 0; reg < 4; ++reg)
      tm[reg] = fmaxf(fmaxf(S[0][reg], S[1][reg]), fmaxf(S[2][reg], S[3][reg]));
    #pragma unroll
    for (int off = 1; off < 16; off <<= 1)
      #pragma unroll
      for (int reg = 0; reg < 4; ++reg)
        tm[reg] = fmaxf(tm[reg], __shfl_xor(tm[reg], off, 64));
    #pragma unroll
    for (int reg = 0; reg < 4; ++reg) {
      float mn = fmaxf(m_run[reg], tm[reg]);
      al[reg] = __expf(m_run[reg] - mn);
      m_run[reg] = mn;
      ts[reg] = 0.f;
    }
    #pragma unroll
    for (int nt = 0; nt < 4; ++nt)
      #pragma unroll
      for (int reg = 0; reg < 4; ++reg) {
        float p = __expf(S[nt][reg] - m_run[reg]);
        S[nt][reg] = p;
        ts[reg] += p;
      }
    #pragma unroll
    for (int off = 1; off < 16; off <<= 1)
      #pragma unroll
      for (int reg = 0; reg < 4; ++reg)
        ts[reg] += __shfl_xor(ts[reg], off, 64);
    #pragma unroll
    for (int reg = 0; reg < 4; ++reg)
      l_run[reg] = l_run[reg] * al[reg] + ts[reg];
    #pragma unroll
    for (int dt = 0; dt < 4; ++dt)
      #pragma unroll
      for (int reg = 0; reg < 4; ++reg)
        O[dt][reg] *= al[reg];

    // ---- P (C-layout) -> per-wave LDS -> A-layout frags
    u16* pb = Pb[wv];
    #pragma unroll
    for (int nt = 0; nt < 4; ++nt)
      #pragma unroll
      for (int reg = 0; reg < 4; ++reg)
        pb[(g * 4 + reg) * 72 + nt * 16 + r16] = f2bf(S[nt][reg]);

    // ---- PV: V B-frags from pre-shuffled global chunks (coalesced 16B)
    #pragma unroll
    for (int kc = 0; kc < 2; ++kc) {
      short8 pa = *(const short8*)&pb[r16 * 72 + kc * 32 + g * 8];
      #pragma unroll
      for (int dt = 0; dt < 4; ++dt) {
        short8 bv = *(const short8*)(Vf + (((size_t)(bh * 32 + kt * 2 + kc) * 4 + dt) * 512) + lane * 8);
        O[dt] = __builtin_amdgcn_mfma_f32_16x16x32_bf16(pa, bv, O[dt], 0, 0, 0);
      }
    }
  }

  #pragma unroll
  for (int reg = 0; reg < 4; ++reg) l_run[reg] = 1.0f / l_run[reg];
  #pragma unroll
  for (int dt = 0; dt < 4; ++dt)
    #pragma unroll
    for (int reg = 0; reg < 4; ++reg)
      out[(size_t)(b * SB + qbase + reg) * DM + h * DH + dt * 16 + r16] =
          O[dt][reg] * l_run[reg];
}

extern "C" void kernel_launch(void* const* d_in, const int* in_sizes, int n_in,
                              void* d_out, int out_size, void* d_ws, size_t ws_size,
                              hipStream_t stream) {
  const float* x     = (const float*)d_in[0];
  const float* gamma = (const float*)d_in[1];
  const float* beta  = (const float*)d_in[2];
  const float* w_pos = (const float*)d_in[3];
  const float* w_tok = (const float*)d_in[4];
  const float* bt    = (const float*)d_in[5];
  float* out = (float*)d_out;
  float* ws  = (float*)d_ws;
  const unsigned M1 = 1u << 20;
  const float IS = 11.313708498984761f;  // sqrt(2*dh)

  // Workspace (f32 units, 19M total = 76 MB; lifetimes disjoint where overlaid):
  float*    PE    = ws;                               // [0,1M)    dead after pack
  _Float16* peH   = (_Float16*)(ws + 1 * M1);         // [1,1.5M)  dead after pos gemm
  _Float16* peL   = (_Float16*)(ws + 1 * M1 + M1/2);  // [1.5,2M)
  _Float16* wpH   = (_Float16*)(ws + 2 * M1);         // [2,3M)
  _Float16* wpL   = (_Float16*)(ws + 3 * M1);         // [3,4M)
  u16*      posKH = (u16*)(ws + 4 * M1);              // [4,4.5M)  live -> attn
  u16*      posKL = (u16*)(ws + 4 * M1 + M1/2);       // [4.5,5M)
  u16*      posQH = (u16*)(ws + 5 * M1);              // [5,5.5M)
  u16*      posQL = (u16*)(ws + 5 * M1 + M1/2);       // [5.5,6M)
  float*    XN    = ws + 6 * M1;                      // [6,10M)   dead after pack
  _Float16* xnH   = (_Float16*)(ws + 10 * M1);        // [10,12M)  dead after tok gemm
  _Float16* xnL   = (_Float16*)(ws + 12 * M1);        // [12,14M)
  _Float16* wtH   = (_Float16*)(ws + 14 * M1);        // [14,15.5M)
  _Float16* wtL   = (_Float16*)(ws + 15 * M1 + M1/2); // [15.5,17M)
  u16*      KH    = (u16*)(ws);                       // [0,2M)    over PE/peHL (dead)
  u16*      KL    = (u16*)(ws + 2 * M1);              // [2,4M)    over wpHL (dead)
  u16*      QH    = (u16*)(ws + 6 * M1);              // [6,8M)    over XN (dead)
  u16*      QL    = (u16*)(ws + 8 * M1);              // [8,10M)
  u16*      VH    = (u16*)(ws + 17 * M1);             // [17,19M)  dead after pack_v
  u16*      Vf    = (u16*)(ws + 10 * M1);             // [10,12M)  over xnH (dead)
  float*    btT   = ws + 12 * M1;                     // [12,12.04M) over xnL (dead)

  pe_kernel<<<SB, 256, 0, stream>>>(PE);
  pack16<<<SB / 16, 256, 0, stream>>>(PE, peH, peL, 1.0f);
  pack16<<<(2 * DM) / 16, 256, 0, stream>>>(w_pos, wpH, wpL, 32.0f);
  // pos = pe @ w_pos^T : bands {posK (1/32), posQ (IS/32)}
  gemm16<<<dim3((2 * DM) / GBN, SB / GBM), 256, 0, stream>>>(
      peH, peL, wpH, wpL,
      posKH, posKL, 1.0f / 32.0f,
      posQH, posQL, IS / 32.0f,
      posKH, posKL, 1.0f / 32.0f);
  ln_kernel<<<BB * SB, 256, 0, stream>>>(x, gamma, beta, XN);
  pack16<<<(BB * SB) / 16, 256, 0, stream>>>(XN, xnH, xnL, 1.0f);
  pack16<<<(3 * DM) / 16, 256, 0, stream>>>(w_tok, wtH, wtL, 32.0f);
  // tok = xn @ w_tok^T : bands {K (1/32), Q (IS/32), V hi-only (1/32)}
  gemm16<<<dim3((3 * DM) / GBN, (BB * SB) / GBM), 256, 0, stream>>>(
      xnH, xnL, wtH, wtL,
      KH, KL, 1.0f / 32.0f,
      QH, QL, IS / 32.0f,
      VH, (u16*)nullptr, 1.0f / 32.0f);
  pack_v<<<dim3(SB / 64, NH, BB), 256, 0, stream>>>(VH, Vf);
  btt_kernel<<<NH, 256, 0, stream>>>(bt, btT);
  attn_mfma2<<<BB * NH * (SB / 64), 256, 0, stream>>>(
      KH, KL, posKH, posKL, QH, QL, posQH, posQL, Vf, btT, out);
}

// Round 5
// 388.021 us; speedup vs baseline: 5.0702x; 1.1245x over previous
//
#include <hip/hip_runtime.h>
#include <math.h>

#define SB 1024   // seq len
#define DM 1024   // d_model
#define BB 4      // batch
#define NH 16     // heads
#define DH 64     // head dim
#define ML 1024   // MAX_LEN

typedef __attribute__((ext_vector_type(8))) short short8;
typedef __attribute__((ext_vector_type(8))) _Float16 half8;
typedef __attribute__((ext_vector_type(4))) float f32x4;
typedef unsigned short u16;

__device__ __forceinline__ u16 f2bf(float x) {
  unsigned u = __float_as_uint(x);
  u += 0x7fffu + ((u >> 16) & 1u);
  return (u16)(u >> 16);
}
__device__ __forceinline__ float bf2f(u16 h) { return __uint_as_float((unsigned)h << 16); }

// async global->LDS, 16B per lane; lds base must be wave-uniform (HW adds lane*16)
__device__ __forceinline__ void async16(void* lds, const void* g) {
  __builtin_amdgcn_global_load_lds(
      (const __attribute__((address_space(1))) unsigned*)g,
      (__attribute__((address_space(3))) unsigned*)lds, 16, 0, 0);
}

// ---------------- sinusoidal positional encoding ----------------
__global__ void pe_kernel(float* __restrict__ pe) {
  int p = blockIdx.x;
  for (int i = threadIdx.x; i < DM / 2; i += 256) {
    float div = expf((float)(2 * i) * (-9.210340371976184f / (float)DM));
    float ang = (float)p * div;
    pe[(size_t)p * DM + 2 * i]     = sinf(ang);
    pe[(size_t)p * DM + 2 * i + 1] = cosf(ang);
  }
}

// ---------------- layernorm (fp32 out) ----------------
__device__ __forceinline__ float block_sum256(float s, float* red) {
  #pragma unroll
  for (int o = 32; o > 0; o >>= 1) s += __shfl_down(s, o, 64);
  int t = threadIdx.x;
  if ((t & 63) == 0) red[t >> 6] = s;
  __syncthreads();
  float tot = red[0] + red[1] + red[2] + red[3];
  __syncthreads();
  return tot;
}

__global__ __launch_bounds__(256) void ln_kernel(const float* __restrict__ x,
    const float* __restrict__ gamma, const float* __restrict__ beta,
    float* __restrict__ xn) {
  __shared__ float red[4];
  int row = blockIdx.x;
  const float4* xr = (const float4*)(x + (size_t)row * DM);
  int t = threadIdx.x;
  float4 v = xr[t];
  float mu = block_sum256(v.x + v.y + v.z + v.w, red) * (1.0f / DM);
  float4 d = {v.x - mu, v.y - mu, v.z - mu, v.w - mu};
  float var = block_sum256(d.x*d.x + d.y*d.y + d.z*d.z + d.w*d.w, red) * (1.0f / DM);
  float rstd = rsqrtf(var + 1e-5f);
  float4 g  = ((const float4*)gamma)[t];
  float4 bb = ((const float4*)beta)[t];
  float4 o = {d.x * rstd * g.x + bb.x, d.y * rstd * g.y + bb.y,
              d.z * rstd * g.z + bb.z, d.w * rstd * g.w + bb.w};
  ((float4*)(xn + (size_t)row * DM))[t] = o;
}

// ---------------- pack fp32 [R][1024] -> split-fp16 frag-chunk planes ----------------
__global__ __launch_bounds__(256) void pack16(const float* __restrict__ src,
    _Float16* __restrict__ dH, _Float16* __restrict__ dL, float scale) {
  int rt = blockIdx.x;
  int t = threadIdx.x;
  int r16 = t >> 4, ks = t & 15;
  const float* sp = src + (size_t)(rt * 16 + r16) * 1024 + ks * 64;
  float v[64];
  #pragma unroll
  for (int i = 0; i < 16; ++i) {
    float4 f = *(const float4*)(sp + i * 4);
    v[i*4+0] = f.x; v[i*4+1] = f.y; v[i*4+2] = f.z; v[i*4+3] = f.w;
  }
  #pragma unroll
  for (int hf = 0; hf < 2; ++hf) {
    int kt = ks * 2 + hf;
    #pragma unroll
    for (int gg = 0; gg < 4; ++gg) {
      half8 hv, lv;
      #pragma unroll
      for (int j = 0; j < 8; ++j) {
        float x = v[hf * 32 + gg * 8 + j] * scale;
        _Float16 h = (_Float16)x;
        hv[j] = h;
        lv[j] = (_Float16)(x - (float)h);
      }
      size_t off = ((size_t)(rt * 32 + kt) * 64 + r16 + gg * 16) * 8;
      *(half8*)(dH + off) = hv;
      *(half8*)(dL + off) = lv;
    }
  }
}

// ---------------- split-fp16 MFMA GEMM ----------------
#define GBM 128
#define GBN 256

__global__ __launch_bounds__(256, 2) void gemm16(
    const _Float16* __restrict__ AH, const _Float16* __restrict__ AL,
    const _Float16* __restrict__ BH, const _Float16* __restrict__ BL,
    u16* __restrict__ o0H, u16* __restrict__ o0L, float s0,
    u16* __restrict__ o1H, u16* __restrict__ o1L, float s1,
    u16* __restrict__ o2H, u16* __restrict__ o2L, float s2) {
  __shared__ _Float16 L[32 * 512];
  int t = threadIdx.x;
  int wv = t >> 6, lane = t & 63;
  int wm = wv >> 1, wn = wv & 1;
  int r16 = lane & 15, g = lane >> 4;
  int m0 = blockIdx.y * GBM;
  int n0 = blockIdx.x * GBN;
  int mt0 = m0 >> 4, nt0 = n0 >> 4;

  f32x4 acc[4][8];
  #pragma unroll
  for (int i = 0; i < 4; ++i)
    #pragma unroll
    for (int j = 0; j < 8; ++j) acc[i][j] = (f32x4){0.f, 0.f, 0.f, 0.f};

  for (int kt = 0; kt < 32; ++kt) {
    __syncthreads();
    #pragma unroll
    for (int rd = 0; rd < 8; ++rd) {
      int ci = rd * 4 + wv;
      const _Float16* src;
      if (ci < 16) {
        int mt = ci >> 1, pl = ci & 1;
        const _Float16* P = pl ? AL : AH;
        src = P + ((size_t)((mt0 + mt) * 32 + kt) * 64 + lane) * 8;
      } else {
        int nt = ci - 16;
        src = BH + ((size_t)((nt0 + nt) * 32 + kt) * 64 + lane) * 8;
      }
      async16(&L[ci * 512], src);
    }
    half8 blo[8];
    #pragma unroll
    for (int j = 0; j < 8; ++j) {
      int ntg = nt0 + wn * 8 + j;
      blo[j] = *(const half8*)(BL + ((size_t)(ntg * 32 + kt) * 64 + lane) * 8);
    }
    __syncthreads();

    half8 ah[4], al[4];
    #pragma unroll
    for (int i = 0; i < 4; ++i) {
      ah[i] = *(const half8*)&L[(((wm * 4 + i) * 2 + 0) * 512) + lane * 8];
      al[i] = *(const half8*)&L[(((wm * 4 + i) * 2 + 1) * 512) + lane * 8];
    }
    #pragma unroll
    for (int j = 0; j < 8; ++j) {
      half8 bh = *(const half8*)&L[((16 + wn * 8 + j) * 512) + lane * 8];
      #pragma unroll
      for (int i = 0; i < 4; ++i) {
        acc[i][j] = __builtin_amdgcn_mfma_f32_16x16x32_f16(ah[i], bh, acc[i][j], 0, 0, 0);
        acc[i][j] = __builtin_amdgcn_mfma_f32_16x16x32_f16(al[i], bh, acc[i][j], 0, 0, 0);
        acc[i][j] = __builtin_amdgcn_mfma_f32_16x16x32_f16(ah[i], blo[j], acc[i][j], 0, 0, 0);
      }
    }
  }

  #pragma unroll
  for (int i = 0; i < 4; ++i)
    #pragma unroll
    for (int j = 0; j < 8; ++j) {
      int col = n0 + wn * 128 + j * 16 + r16;
      int band = col >> 10, lc = col & 1023;
      float sc = band == 0 ? s0 : band == 1 ? s1 : s2;
      u16* oh = band == 0 ? o0H : band == 1 ? o1H : o2H;
      u16* ol = band == 0 ? o0L : band == 1 ? o1L : o2L;
      #pragma unroll
      for (int reg = 0; reg < 4; ++reg) {
        int row = m0 + wm * 64 + i * 16 + g * 4 + reg;
        float c = acc[i][j][reg] * sc;
        u16 hi = f2bf(c);
        oh[(size_t)row * 1024 + lc] = hi;
        if (ol) ol[(size_t)row * 1024 + lc] = f2bf(c - bf2f(hi));
      }
    }
}

// ---------------- pack V (bf16 [B*S][1024] cols h*64+d) -> frag chunks ----------------
__global__ __launch_bounds__(256) void pack_v(const u16* __restrict__ VHg,
    u16* __restrict__ Vf) {
  int sg = blockIdx.x;
  int h = blockIdx.y, b = blockIdx.z;
  int bh = b * NH + h;
  int t = threadIdx.x;
  int r = t >> 2, q = t & 3;
  int s = sg * 64 + r;
  int kc = s >> 5, g = (s >> 3) & 3, j = s & 7;
  const u16* sp = VHg + (size_t)(b * SB + s) * 1024 + h * 64 + q * 16;
  u16 vv[16];
  *(short8*)&vv[0] = *(const short8*)sp;
  *(short8*)&vv[8] = *(const short8*)(sp + 8);
  u16* dp = Vf + ((size_t)(bh * 32 + kc) * 4 + q) * 512 + g * 128 + j;
  #pragma unroll
  for (int e = 0; e < 16; ++e) dp[e * 8] = vv[e];
}

// ---------------- pack K split-bf16 planes -> MFMA B-frag chunks ----------------
// tok (z<BB): Ktf*[ ((bh*64+st)*2+c)*512 + lane*8 + j ] = K*[(b*SB+st*16+(lane&15))*1024 + h*64 + c*32 + (lane>>4)*8 + j]
// pos (z==BB): Kpf*[ ((h*64+st)*2+c)*512 + ... ] likewise from pos planes.
__global__ __launch_bounds__(256) void pack_kf(
    const u16* __restrict__ KH, const u16* __restrict__ KL,
    const u16* __restrict__ pKH, const u16* __restrict__ pKL,
    u16* __restrict__ KtfH, u16* __restrict__ KtfL,
    u16* __restrict__ KpfH, u16* __restrict__ KpfL) {
  int sq = blockIdx.x;           // st quarter: 16 sTiles
  int h = blockIdx.y, z = blockIdx.z;
  int t = threadIdx.x;
  int u = t >> 6, lane = t & 63;
  #pragma unroll
  for (int it = 0; it < 16; ++it) {
    int uu = it * 4 + u;         // 0..63
    int stl = uu >> 2, c = (uu >> 1) & 1, pl = uu & 1;
    int st = sq * 16 + stl;
    size_t roff = (size_t)(st * 16 + (lane & 15)) * 1024 + h * 64 + c * 32 + (lane >> 4) * 8;
    const u16* src;
    u16* dst;
    if (z < BB) {
      src = (pl ? KL : KH) + (size_t)z * SB * 1024 + roff;
      dst = (pl ? KtfL : KtfH) + ((size_t)((z * NH + h) * 64 + st) * 2 + c) * 512 + lane * 8;
    } else {
      src = (pl ? pKL : pKH) + roff;
      dst = (pl ? KpfL : KpfH) + ((size_t)(h * 64 + st) * 2 + c) * 512 + lane * 8;
    }
    *(short8*)dst = *(const short8*)src;
  }
}

// ---------------- bias table transpose: btT[h][rel] ----------------
__global__ __launch_bounds__(256) void btt_kernel(
    const float* __restrict__ bt, float* __restrict__ btT) {
  int h = blockIdx.x;
  for (int r = threadIdx.x; r < 2 * ML; r += 256)
    btT[(size_t)h * (2 * ML) + r] = bt[(size_t)r * NH + h];
}

// ---------------- MFMA flash attention v3: barrier-free K-loop ----------------
// K and V B-frags come straight from pre-packed global chunks (L1/L2-hot),
// no LDS staging, no __syncthreads in the main loop.
__global__ __launch_bounds__(256) void attn_mfma3(
    const u16* __restrict__ KtfH, const u16* __restrict__ KtfL,  // [BH][64][2][512]
    const u16* __restrict__ KpfH, const u16* __restrict__ KpfL,  // [H][64][2][512]
    const u16* __restrict__ QHg, const u16* __restrict__ QLg,    // [B*S][1024] (x IS)
    const u16* __restrict__ pQH, const u16* __restrict__ pQL,    // [S][1024] (x IS)
    const u16* __restrict__ Vf,                                   // [BH][32][4][512]
    const float* __restrict__ btT, float* __restrict__ out) {
  __shared__ u16 Pb[4][16 * 72];
  int bid = blockIdx.x;
  int qt = bid & 15;
  int h  = (bid >> 4) & 15;
  int b  = bid >> 8;
  int q0 = qt * 64;
  int t = threadIdx.x;
  int wv = t >> 6, lane = t & 63;
  int g = lane >> 4, r16 = lane & 15;
  int bh = b * NH + h;

  // ---- Q fragments (A-layout), hi/lo straight from split planes
  int qrow = q0 + wv * 16 + r16;
  short8 qhi[4], qlo[4];
  #pragma unroll
  for (int c = 0; c < 4; ++c) {
    if (c < 2) {
      size_t off = (size_t)(b * SB + qrow) * 1024 + h * DH + c * 32 + g * 8;
      qhi[c] = *(const short8*)(QHg + off);
      qlo[c] = *(const short8*)(QLg + off);
    } else {
      size_t off = (size_t)qrow * 1024 + h * DH + (c - 2) * 32 + g * 8;
      qhi[c] = *(const short8*)(pQH + off);
      qlo[c] = *(const short8*)(pQL + off);
    }
  }

  f32x4 O[4];
  #pragma unroll
  for (int dt = 0; dt < 4; ++dt) O[dt] = (f32x4){0.f, 0.f, 0.f, 0.f};
  float m_run[4] = {-3e38f, -3e38f, -3e38f, -3e38f};
  float l_run[4] = {0.f, 0.f, 0.f, 0.f};

  const float* bts = btT + (size_t)h * (2 * ML);
  const u16* KtH0 = KtfH + (size_t)(bh * 64) * 1024 + lane * 8;   // stride per sTile: 2*512
  const u16* KtL0 = KtfL + (size_t)(bh * 64) * 1024 + lane * 8;
  const u16* KpH0 = KpfH + (size_t)(h * 64) * 1024 + lane * 8;
  const u16* KpL0 = KpfL + (size_t)(h * 64) * 1024 + lane * 8;
  int qbase = q0 + wv * 16 + g * 4;

  for (int kt = 0; kt < 16; ++kt) {
    // ---- QK^T: S = (Qhi+Qlo).(Khi+Klo), 3-term, B-frags direct from global
    f32x4 S[4];
    #pragma unroll
    for (int nt = 0; nt < 4; ++nt) {
      int stg = kt * 4 + nt;
      f32x4 acc = (f32x4){0.f, 0.f, 0.f, 0.f};
      #pragma unroll
      for (int c = 0; c < 4; ++c) {
        short8 bhi, blo;
        if (c < 2) {
          size_t off = ((size_t)stg * 2 + c) * 512;
          bhi = *(const short8*)(KtH0 + off);
          blo = *(const short8*)(KtL0 + off);
        } else {
          size_t off = ((size_t)stg * 2 + (c - 2)) * 512;
          bhi = *(const short8*)(KpH0 + off);
          blo = *(const short8*)(KpL0 + off);
        }
        acc = __builtin_amdgcn_mfma_f32_16x16x32_bf16(qhi[c], bhi, acc, 0, 0, 0);
        acc = __builtin_amdgcn_mfma_f32_16x16x32_bf16(qlo[c], bhi, acc, 0, 0, 0);
        acc = __builtin_amdgcn_mfma_f32_16x16x32_bf16(qhi[c], blo, acc, 0, 0, 0);
      }
      S[nt] = acc;
    }

    // ---- rel-pos bias
    int k0 = kt * 64;
    #pragma unroll
    for (int nt = 0; nt < 4; ++nt) {
      int kk = k0 + nt * 16 + r16;
      #pragma unroll
      for (int reg = 0; reg < 4; ++reg)
        S[nt][reg] += bts[ML + kk - (qbase + reg)];
    }

    // ---- online softmax
    float tm[4], al[4], ts[4];
    #pragma unroll
    for (int reg = 0; reg < 4; ++reg)
      tm[reg] = fmaxf(fmaxf(S[0][reg], S[1][reg]), fmaxf(S[2][reg], S[3][reg]));
    #pragma unroll
    for (int off = 1; off < 16; off <<= 1)
      #pragma unroll
      for (int reg = 0; reg < 4; ++reg)
        tm[reg] = fmaxf(tm[reg], __shfl_xor(tm[reg], off, 64));
    #pragma unroll
    for (int reg = 0; reg < 4; ++reg) {
      float mn = fmaxf(m_run[reg], tm[reg]);
      al[reg] = __expf(m_run[reg] - mn);
      m_run[reg] = mn;
      ts[reg] = 0.f;
    }
    #pragma unroll
    for (int nt = 0; nt < 4; ++nt)
      #pragma unroll
      for (int reg = 0; reg < 4; ++reg) {
        float p = __expf(S[nt][reg] - m_run[reg]);
        S[nt][reg] = p;
        ts[reg] += p;
      }
    #pragma unroll
    for (int off = 1; off < 16; off <<= 1)
      #pragma unroll
      for (int reg = 0; reg < 4; ++reg)
        ts[reg] += __shfl_xor(ts[reg], off, 64);
    #pragma unroll
    for (int reg = 0; reg < 4; ++reg)
      l_run[reg] = l_run[reg] * al[reg] + ts[reg];
    #pragma unroll
    for (int dt = 0; dt < 4; ++dt)
      #pragma unroll
      for (int reg = 0; reg < 4; ++reg)
        O[dt][reg] *= al[reg];

    // ---- P (C-layout) -> per-wave LDS -> A-layout frags (wave-local ordering)
    u16* pb = Pb[wv];
    #pragma unroll
    for (int nt = 0; nt < 4; ++nt)
      #pragma unroll
      for (int reg = 0; reg < 4; ++reg)
        pb[(g * 4 + reg) * 72 + nt * 16 + r16] = f2bf(S[nt][reg]);

    // ---- PV: V B-frags from pre-shuffled global chunks
    #pragma unroll
    for (int kc = 0; kc < 2; ++kc) {
      short8 pa = *(const short8*)&pb[r16 * 72 + kc * 32 + g * 8];
      #pragma unroll
      for (int dt = 0; dt < 4; ++dt) {
        short8 bv = *(const short8*)(Vf + (((size_t)(bh * 32 + kt * 2 + kc) * 4 + dt) * 512) + lane * 8);
        O[dt] = __builtin_amdgcn_mfma_f32_16x16x32_bf16(pa, bv, O[dt], 0, 0, 0);
      }
    }
  }

  #pragma unroll
  for (int reg = 0; reg < 4; ++reg) l_run[reg] = 1.0f / l_run[reg];
  #pragma unroll
  for (int dt = 0; dt < 4; ++dt)
    #pragma unroll
    for (int reg = 0; reg < 4; ++reg)
      out[(size_t)(b * SB + qbase + reg) * DM + h * DH + dt * 16 + r16] =
          O[dt][reg] * l_run[reg];
}

extern "C" void kernel_launch(void* const* d_in, const int* in_sizes, int n_in,
                              void* d_out, int out_size, void* d_ws, size_t ws_size,
                              hipStream_t stream) {
  const float* x     = (const float*)d_in[0];
  const float* gamma = (const float*)d_in[1];
  const float* beta  = (const float*)d_in[2];
  const float* w_pos = (const float*)d_in[3];
  const float* w_tok = (const float*)d_in[4];
  const float* bt    = (const float*)d_in[5];
  float* out = (float*)d_out;
  float* ws  = (float*)d_ws;
  const unsigned M1 = 1u << 20;
  const float IS = 11.313708498984761f;  // sqrt(2*dh)

  // Workspace (f32 units, 19M = 76 MB; overlays only on dead regions):
  float*    PE    = ws;                               // [0,1M)    dead after pack16
  _Float16* peH   = (_Float16*)(ws + 1 * M1);         // [1,1.5M)  dead after pos gemm
  _Float16* peL   = (_Float16*)(ws + 1 * M1 + M1/2);  // [1.5,2M)
  _Float16* wpH   = (_Float16*)(ws + 2 * M1);         // [2,3M)    dead after pos gemm
  _Float16* wpL   = (_Float16*)(ws + 3 * M1);         // [3,4M)
  u16*      posKH = (u16*)(ws + 4 * M1);              // [4,4.5M)  live -> pack_kf
  u16*      posKL = (u16*)(ws + 4 * M1 + M1/2);       // [4.5,5M)
  u16*      posQH = (u16*)(ws + 5 * M1);              // [5,5.5M)  live -> attn
  u16*      posQL = (u16*)(ws + 5 * M1 + M1/2);       // [5.5,6M)
  float*    XN    = ws + 6 * M1;                      // [6,10M)   dead after pack16
  _Float16* xnH   = (_Float16*)(ws + 10 * M1);        // [10,12M)  dead after tok gemm
  _Float16* xnL   = (_Float16*)(ws + 12 * M1);        // [12,14M)  dead after tok gemm
  _Float16* wtH   = (_Float16*)(ws + 14 * M1);        // [14,15.5M) dead after tok gemm
  _Float16* wtL   = (_Float16*)(ws + 15 * M1 + M1/2); // [15.5,17M)
  u16*      KH    = (u16*)(ws);                       // [0,2M)    over PE/peHL; live -> pack_kf
  u16*      KL    = (u16*)(ws + 2 * M1);              // [2,4M)    over wpHL; live -> pack_kf
  u16*      QH    = (u16*)(ws + 6 * M1);              // [6,8M)    over XN; live -> attn
  u16*      QL    = (u16*)(ws + 8 * M1);              // [8,10M)
  u16*      VH    = (u16*)(ws + 17 * M1);             // [17,19M)  dead after pack_v
  u16*      Vf    = (u16*)(ws + 10 * M1);             // [10,12M)  over xnH; live -> attn
  float*    btT   = ws + 12 * M1;                     // [12,12.25M) over xnL
  u16*      KpfH  = (u16*)(ws + 12 * M1 + M1/4);      // [12.25,12.75M) 2 MB
  u16*      KpfL  = (u16*)(ws + 12 * M1 + 3*M1/4);    // [12.75,13.25M)
  u16*      KtfH  = (u16*)(ws + 13 * M1 + M1/4);      // [13.25,15.25M) 8 MB (over wtH tail ok)
  u16*      KtfL  = (u16*)(ws + 15 * M1 + M1/4);      // [15.25,17.25M) (over wtL + VH head, after pack_v)

  pe_kernel<<<SB, 256, 0, stream>>>(PE);
  pack16<<<SB / 16, 256, 0, stream>>>(PE, peH, peL, 1.0f);
  pack16<<<(2 * DM) / 16, 256, 0, stream>>>(w_pos, wpH, wpL, 32.0f);
  gemm16<<<dim3((2 * DM) / GBN, SB / GBM), 256, 0, stream>>>(
      peH, peL, wpH, wpL,
      posKH, posKL, 1.0f / 32.0f,
      posQH, posQL, IS / 32.0f,
      posKH, posKL, 1.0f / 32.0f);
  ln_kernel<<<BB * SB, 256, 0, stream>>>(x, gamma, beta, XN);
  pack16<<<(BB * SB) / 16, 256, 0, stream>>>(XN, xnH, xnL, 1.0f);
  pack16<<<(3 * DM) / 16, 256, 0, stream>>>(w_tok, wtH, wtL, 32.0f);
  gemm16<<<dim3((3 * DM) / GBN, (BB * SB) / GBM), 256, 0, stream>>>(
      xnH, xnL, wtH, wtL,
      KH, KL, 1.0f / 32.0f,
      QH, QL, IS / 32.0f,
      VH, (u16*)nullptr, 1.0f / 32.0f);
  pack_v<<<dim3(SB / 64, NH, BB), 256, 0, stream>>>(VH, Vf);   // must precede pack_kf (KtfL overlays VH head)
  pack_kf<<<dim3(4, NH, BB + 1), 256, 0, stream>>>(KH, KL, posKH, posKL,
                                                   KtfH, KtfL, KpfH, KpfL);
  btt_kernel<<<NH, 256, 0, stream>>>(bt, btT);
  attn_mfma3<<<BB * NH * (SB / 64), 256, 0, stream>>>(
      KtfH, KtfL, KpfH, KpfL, QH, QL, posQH, posQL, Vf, btT, out);
}

// Round 6
// 369.784 us; speedup vs baseline: 5.3203x; 1.0493x over previous
//
#include <hip/hip_runtime.h>
#include <math.h>

#define SB 1024   // seq len
#define DM 1024   // d_model
#define BB 4      // batch
#define NH 16     // heads
#define DH 64     // head dim
#define ML 1024   // MAX_LEN

typedef __attribute__((ext_vector_type(8))) short short8;
typedef __attribute__((ext_vector_type(8))) _Float16 half8;
typedef __attribute__((ext_vector_type(4))) float f32x4;
typedef unsigned short u16;

__device__ __forceinline__ u16 f2bf(float x) {
  unsigned u = __float_as_uint(x);
  u += 0x7fffu + ((u >> 16) & 1u);
  return (u16)(u >> 16);
}
__device__ __forceinline__ float bf2f(u16 h) { return __uint_as_float((unsigned)h << 16); }

// async global->LDS, 16B per lane; lds base must be wave-uniform (HW adds lane*16)
__device__ __forceinline__ void async16(void* lds, const void* g) {
  __builtin_amdgcn_global_load_lds(
      (const __attribute__((address_space(1))) unsigned*)g,
      (__attribute__((address_space(3))) unsigned*)lds, 16, 0, 0);
}

// ---------------- sinusoidal positional encoding ----------------
__global__ void pe_kernel(float* __restrict__ pe) {
  int p = blockIdx.x;
  for (int i = threadIdx.x; i < DM / 2; i += 256) {
    float div = expf((float)(2 * i) * (-9.210340371976184f / (float)DM));
    float ang = (float)p * div;
    pe[(size_t)p * DM + 2 * i]     = sinf(ang);
    pe[(size_t)p * DM + 2 * i + 1] = cosf(ang);
  }
}

// ---------------- layernorm (fp32 out) ----------------
__device__ __forceinline__ float block_sum256(float s, float* red) {
  #pragma unroll
  for (int o = 32; o > 0; o >>= 1) s += __shfl_down(s, o, 64);
  int t = threadIdx.x;
  if ((t & 63) == 0) red[t >> 6] = s;
  __syncthreads();
  float tot = red[0] + red[1] + red[2] + red[3];
  __syncthreads();
  return tot;
}

__global__ __launch_bounds__(256) void ln_kernel(const float* __restrict__ x,
    const float* __restrict__ gamma, const float* __restrict__ beta,
    float* __restrict__ xn) {
  __shared__ float red[4];
  int row = blockIdx.x;
  const float4* xr = (const float4*)(x + (size_t)row * DM);
  int t = threadIdx.x;
  float4 v = xr[t];
  float mu = block_sum256(v.x + v.y + v.z + v.w, red) * (1.0f / DM);
  float4 d = {v.x - mu, v.y - mu, v.z - mu, v.w - mu};
  float var = block_sum256(d.x*d.x + d.y*d.y + d.z*d.z + d.w*d.w, red) * (1.0f / DM);
  float rstd = rsqrtf(var + 1e-5f);
  float4 g  = ((const float4*)gamma)[t];
  float4 bb = ((const float4*)beta)[t];
  float4 o = {d.x * rstd * g.x + bb.x, d.y * rstd * g.y + bb.y,
              d.z * rstd * g.z + bb.z, d.w * rstd * g.w + bb.w};
  ((float4*)(xn + (size_t)row * DM))[t] = o;
}

// ---------------- pack fp32 [R][1024] -> split-fp16 frag-chunk planes ----------------
__global__ __launch_bounds__(256) void pack16(const float* __restrict__ src,
    _Float16* __restrict__ dH, _Float16* __restrict__ dL, float scale) {
  int rt = blockIdx.x;
  int t = threadIdx.x;
  int r16 = t >> 4, ks = t & 15;
  const float* sp = src + (size_t)(rt * 16 + r16) * 1024 + ks * 64;
  float v[64];
  #pragma unroll
  for (int i = 0; i < 16; ++i) {
    float4 f = *(const float4*)(sp + i * 4);
    v[i*4+0] = f.x; v[i*4+1] = f.y; v[i*4+2] = f.z; v[i*4+3] = f.w;
  }
  #pragma unroll
  for (int hf = 0; hf < 2; ++hf) {
    int kt = ks * 2 + hf;
    #pragma unroll
    for (int gg = 0; gg < 4; ++gg) {
      half8 hv, lv;
      #pragma unroll
      for (int j = 0; j < 8; ++j) {
        float x = v[hf * 32 + gg * 8 + j] * scale;
        _Float16 h = (_Float16)x;
        hv[j] = h;
        lv[j] = (_Float16)(x - (float)h);
      }
      size_t off = ((size_t)(rt * 32 + kt) * 64 + r16 + gg * 16) * 8;
      *(half8*)(dH + off) = hv;
      *(half8*)(dL + off) = lv;
    }
  }
}

// ---------------- split-fp16 MFMA GEMM ----------------
#define GBM 128
#define GBN 256

__global__ __launch_bounds__(256, 2) void gemm16(
    const _Float16* __restrict__ AH, const _Float16* __restrict__ AL,
    const _Float16* __restrict__ BH, const _Float16* __restrict__ BL,
    u16* __restrict__ o0H, u16* __restrict__ o0L, float s0,
    u16* __restrict__ o1H, u16* __restrict__ o1L, float s1,
    u16* __restrict__ o2H, u16* __restrict__ o2L, float s2) {
  __shared__ _Float16 L[32 * 512];
  int t = threadIdx.x;
  int wv = t >> 6, lane = t & 63;
  int wm = wv >> 1, wn = wv & 1;
  int r16 = lane & 15, g = lane >> 4;
  int m0 = blockIdx.y * GBM;
  int n0 = blockIdx.x * GBN;
  int mt0 = m0 >> 4, nt0 = n0 >> 4;

  f32x4 acc[4][8];
  #pragma unroll
  for (int i = 0; i < 4; ++i)
    #pragma unroll
    for (int j = 0; j < 8; ++j) acc[i][j] = (f32x4){0.f, 0.f, 0.f, 0.f};

  for (int kt = 0; kt < 32; ++kt) {
    __syncthreads();
    #pragma unroll
    for (int rd = 0; rd < 8; ++rd) {
      int ci = rd * 4 + wv;
      const _Float16* src;
      if (ci < 16) {
        int mt = ci >> 1, pl = ci & 1;
        const _Float16* P = pl ? AL : AH;
        src = P + ((size_t)((mt0 + mt) * 32 + kt) * 64 + lane) * 8;
      } else {
        int nt = ci - 16;
        src = BH + ((size_t)((nt0 + nt) * 32 + kt) * 64 + lane) * 8;
      }
      async16(&L[ci * 512], src);
    }
    half8 blo[8];
    #pragma unroll
    for (int j = 0; j < 8; ++j) {
      int ntg = nt0 + wn * 8 + j;
      blo[j] = *(const half8*)(BL + ((size_t)(ntg * 32 + kt) * 64 + lane) * 8);
    }
    __syncthreads();

    half8 ah[4], al[4];
    #pragma unroll
    for (int i = 0; i < 4; ++i) {
      ah[i] = *(const half8*)&L[(((wm * 4 + i) * 2 + 0) * 512) + lane * 8];
      al[i] = *(const half8*)&L[(((wm * 4 + i) * 2 + 1) * 512) + lane * 8];
    }
    #pragma unroll
    for (int j = 0; j < 8; ++j) {
      half8 bh = *(const half8*)&L[((16 + wn * 8 + j) * 512) + lane * 8];
      #pragma unroll
      for (int i = 0; i < 4; ++i) {
        acc[i][j] = __builtin_amdgcn_mfma_f32_16x16x32_f16(ah[i], bh, acc[i][j], 0, 0, 0);
        acc[i][j] = __builtin_amdgcn_mfma_f32_16x16x32_f16(al[i], bh, acc[i][j], 0, 0, 0);
        acc[i][j] = __builtin_amdgcn_mfma_f32_16x16x32_f16(ah[i], blo[j], acc[i][j], 0, 0, 0);
      }
    }
  }

  #pragma unroll
  for (int i = 0; i < 4; ++i)
    #pragma unroll
    for (int j = 0; j < 8; ++j) {
      int col = n0 + wn * 128 + j * 16 + r16;
      int band = col >> 10, lc = col & 1023;
      float sc = band == 0 ? s0 : band == 1 ? s1 : s2;
      u16* oh = band == 0 ? o0H : band == 1 ? o1H : o2H;
      u16* ol = band == 0 ? o0L : band == 1 ? o1L : o2L;
      #pragma unroll
      for (int reg = 0; reg < 4; ++reg) {
        int row = m0 + wm * 64 + i * 16 + g * 4 + reg;
        float c = acc[i][j][reg] * sc;
        u16 hi = f2bf(c);
        oh[(size_t)row * 1024 + lc] = hi;
        if (ol) ol[(size_t)row * 1024 + lc] = f2bf(c - bf2f(hi));
      }
    }
}

// ---------------- pack V (bf16 [B*S][1024] cols h*64+d) -> frag chunks ----------------
__global__ __launch_bounds__(256) void pack_v(const u16* __restrict__ VHg,
    u16* __restrict__ Vf) {
  int sg = blockIdx.x;
  int h = blockIdx.y, b = blockIdx.z;
  int bh = b * NH + h;
  int t = threadIdx.x;
  int r = t >> 2, q = t & 3;
  int s = sg * 64 + r;
  int kc = s >> 5, g = (s >> 3) & 3, j = s & 7;
  const u16* sp = VHg + (size_t)(b * SB + s) * 1024 + h * 64 + q * 16;
  u16 vv[16];
  *(short8*)&vv[0] = *(const short8*)sp;
  *(short8*)&vv[8] = *(const short8*)(sp + 8);
  u16* dp = Vf + ((size_t)(bh * 32 + kc) * 4 + q) * 512 + g * 128 + j;
  #pragma unroll
  for (int e = 0; e < 16; ++e) dp[e * 8] = vv[e];
}

// ---------------- pack K split-bf16 planes -> MFMA B-frag chunks ----------------
__global__ __launch_bounds__(256) void pack_kf(
    const u16* __restrict__ KH, const u16* __restrict__ KL,
    const u16* __restrict__ pKH, const u16* __restrict__ pKL,
    u16* __restrict__ KtfH, u16* __restrict__ KtfL,
    u16* __restrict__ KpfH, u16* __restrict__ KpfL) {
  int sq = blockIdx.x;
  int h = blockIdx.y, z = blockIdx.z;
  int t = threadIdx.x;
  int u = t >> 6, lane = t & 63;
  #pragma unroll
  for (int it = 0; it < 16; ++it) {
    int uu = it * 4 + u;
    int stl = uu >> 2, c = (uu >> 1) & 1, pl = uu & 1;
    int st = sq * 16 + stl;
    size_t roff = (size_t)(st * 16 + (lane & 15)) * 1024 + h * 64 + c * 32 + (lane >> 4) * 8;
    const u16* src;
    u16* dst;
    if (z < BB) {
      src = (pl ? KL : KH) + (size_t)z * SB * 1024 + roff;
      dst = (pl ? KtfL : KtfH) + ((size_t)((z * NH + h) * 64 + st) * 2 + c) * 512 + lane * 8;
    } else {
      src = (pl ? pKL : pKH) + roff;
      dst = (pl ? KpfL : KpfH) + ((size_t)(h * 64 + st) * 2 + c) * 512 + lane * 8;
    }
    *(short8*)dst = *(const short8*)src;
  }
}

// ---------------- bias table transpose: btT[h][rel] ----------------
__global__ __launch_bounds__(256) void btt_kernel(
    const float* __restrict__ bt, float* __restrict__ btT) {
  int h = blockIdx.x;
  for (int r = threadIdx.x; r < 2 * ML; r += 256)
    btT[(size_t)h * (2 * ML) + r] = bt[(size_t)r * NH + h];
}

// ---------------- MFMA flash attention v4: barrier-free + prefetch scheduling ----------------
// __launch_bounds__(256,4): VGPR cap 128 (occupancy is grid-capped at 4 waves/SIMD
// anyway) so the compiler can keep bias gathers + V frags in flight across phases.
__global__ __launch_bounds__(256, 4) void attn_mfma4(
    const u16* __restrict__ KtfH, const u16* __restrict__ KtfL,  // [BH][64][2][512]
    const u16* __restrict__ KpfH, const u16* __restrict__ KpfL,  // [H][64][2][512]
    const u16* __restrict__ QHg, const u16* __restrict__ QLg,    // [B*S][1024] (x IS)
    const u16* __restrict__ pQH, const u16* __restrict__ pQL,    // [S][1024] (x IS)
    const u16* __restrict__ Vf,                                   // [BH][32][4][512]
    const float* __restrict__ btT, float* __restrict__ out) {
  __shared__ u16 Pb[4][16 * 72];
  int bid = blockIdx.x;
  int qt = bid & 15;
  int h  = (bid >> 4) & 15;
  int b  = bid >> 8;
  int q0 = qt * 64;
  int t = threadIdx.x;
  int wv = t >> 6, lane = t & 63;
  int g = lane >> 4, r16 = lane & 15;
  int bh = b * NH + h;

  // ---- Q fragments (A-layout), hi/lo straight from split planes
  int qrow = q0 + wv * 16 + r16;
  short8 qhi[4], qlo[4];
  #pragma unroll
  for (int c = 0; c < 4; ++c) {
    if (c < 2) {
      size_t off = (size_t)(b * SB + qrow) * 1024 + h * DH + c * 32 + g * 8;
      qhi[c] = *(const short8*)(QHg + off);
      qlo[c] = *(const short8*)(QLg + off);
    } else {
      size_t off = (size_t)qrow * 1024 + h * DH + (c - 2) * 32 + g * 8;
      qhi[c] = *(const short8*)(pQH + off);
      qlo[c] = *(const short8*)(pQL + off);
    }
  }

  f32x4 O[4];
  #pragma unroll
  for (int dt = 0; dt < 4; ++dt) O[dt] = (f32x4){0.f, 0.f, 0.f, 0.f};
  float m_run[4] = {-3e38f, -3e38f, -3e38f, -3e38f};
  float l_run[4] = {0.f, 0.f, 0.f, 0.f};

  const float* bts = btT + (size_t)h * (2 * ML);
  const u16* KtH0 = KtfH + (size_t)(bh * 64) * 1024 + lane * 8;
  const u16* KtL0 = KtfL + (size_t)(bh * 64) * 1024 + lane * 8;
  const u16* KpH0 = KpfH + (size_t)(h * 64) * 1024 + lane * 8;
  const u16* KpL0 = KpfL + (size_t)(h * 64) * 1024 + lane * 8;
  const u16* Vb0  = Vf + (size_t)(bh * 32) * 2048 + lane * 8;
  int qbase = q0 + wv * 16 + g * 4;

  for (int kt = 0; kt < 16; ++kt) {
    int k0 = kt * 64;

    // ---- (a) bias gathers first: 16 independent L1 loads, consumed after QK
    float bias[4][4];
    #pragma unroll
    for (int nt = 0; nt < 4; ++nt) {
      int kk = k0 + nt * 16 + r16;
      #pragma unroll
      for (int reg = 0; reg < 4; ++reg)
        bias[nt][reg] = bts[ML + kk - (qbase + reg)];
    }

    // ---- QK^T: S = (Qhi+Qlo).(Khi+Klo), 3-term, B-frags direct from global
    f32x4 S[4];
    #pragma unroll
    for (int nt = 0; nt < 4; ++nt) {
      int stg = kt * 4 + nt;
      f32x4 acc = (f32x4){0.f, 0.f, 0.f, 0.f};
      #pragma unroll
      for (int c = 0; c < 4; ++c) {
        short8 bhi, blo;
        if (c < 2) {
          size_t off = ((size_t)stg * 2 + c) * 512;
          bhi = *(const short8*)(KtH0 + off);
          blo = *(const short8*)(KtL0 + off);
        } else {
          size_t off = ((size_t)stg * 2 + (c - 2)) * 512;
          bhi = *(const short8*)(KpH0 + off);
          blo = *(const short8*)(KpL0 + off);
        }
        acc = __builtin_amdgcn_mfma_f32_16x16x32_bf16(qhi[c], bhi, acc, 0, 0, 0);
        acc = __builtin_amdgcn_mfma_f32_16x16x32_bf16(qlo[c], bhi, acc, 0, 0, 0);
        acc = __builtin_amdgcn_mfma_f32_16x16x32_bf16(qhi[c], blo, acc, 0, 0, 0);
      }
      S[nt] = acc;
    }

    // ---- (b) V prefetch: 8 chunks issued now, consumed after softmax
    short8 vfrag[2][4];
    #pragma unroll
    for (int kc = 0; kc < 2; ++kc)
      #pragma unroll
      for (int dt = 0; dt < 4; ++dt)
        vfrag[kc][dt] = *(const short8*)(Vb0 + ((size_t)(kt * 2 + kc) * 4 + dt) * 512);

    // ---- bias add
    #pragma unroll
    for (int nt = 0; nt < 4; ++nt)
      #pragma unroll
      for (int reg = 0; reg < 4; ++reg)
        S[nt][reg] += bias[nt][reg];

    // ---- online softmax
    float tm[4], al[4], ts[4];
    #pragma unroll
    for (int reg = 0; reg < 4; ++reg)
      tm[reg] = fmaxf(fmaxf(S[0][reg], S[1][reg]), fmaxf(S[2][reg], S[3][reg]));
    #pragma unroll
    for (int off = 1; off < 16; off <<= 1)
      #pragma unroll
      for (int reg = 0; reg < 4; ++reg)
        tm[reg] = fmaxf(tm[reg], __shfl_xor(tm[reg], off, 64));
    #pragma unroll
    for (int reg = 0; reg < 4; ++reg) {
      float mn = fmaxf(m_run[reg], tm[reg]);
      al[reg] = __expf(m_run[reg] - mn);
      m_run[reg] = mn;
      ts[reg] = 0.f;
    }
    #pragma unroll
    for (int nt = 0; nt < 4; ++nt)
      #pragma unroll
      for (int reg = 0; reg < 4; ++reg) {
        float p = __expf(S[nt][reg] - m_run[reg]);
        S[nt][reg] = p;
        ts[reg] += p;
      }
    #pragma unroll
    for (int off = 1; off < 16; off <<= 1)
      #pragma unroll
      for (int reg = 0; reg < 4; ++reg)
        ts[reg] += __shfl_xor(ts[reg], off, 64);
    #pragma unroll
    for (int reg = 0; reg < 4; ++reg)
      l_run[reg] = l_run[reg] * al[reg] + ts[reg];
    #pragma unroll
    for (int dt = 0; dt < 4; ++dt)
      #pragma unroll
      for (int reg = 0; reg < 4; ++reg)
        O[dt][reg] *= al[reg];

    // ---- P (C-layout) -> per-wave LDS -> A-layout frags (wave-local ordering)
    u16* pb = Pb[wv];
    #pragma unroll
    for (int nt = 0; nt < 4; ++nt)
      #pragma unroll
      for (int reg = 0; reg < 4; ++reg)
        pb[(g * 4 + reg) * 72 + nt * 16 + r16] = f2bf(S[nt][reg]);

    // ---- PV with prefetched V frags
    #pragma unroll
    for (int kc = 0; kc < 2; ++kc) {
      short8 pa = *(const short8*)&pb[r16 * 72 + kc * 32 + g * 8];
      #pragma unroll
      for (int dt = 0; dt < 4; ++dt)
        O[dt] = __builtin_amdgcn_mfma_f32_16x16x32_bf16(pa, vfrag[kc][dt], O[dt], 0, 0, 0);
    }
  }

  #pragma unroll
  for (int reg = 0; reg < 4; ++reg) l_run[reg] = 1.0f / l_run[reg];
  #pragma unroll
  for (int dt = 0; dt < 4; ++dt)
    #pragma unroll
    for (int reg = 0; reg < 4; ++reg)
      out[(size_t)(b * SB + qbase + reg) * DM + h * DH + dt * 16 + r16] =
          O[dt][reg] * l_run[reg];
}

extern "C" void kernel_launch(void* const* d_in, const int* in_sizes, int n_in,
                              void* d_out, int out_size, void* d_ws, size_t ws_size,
                              hipStream_t stream) {
  const float* x     = (const float*)d_in[0];
  const float* gamma = (const float*)d_in[1];
  const float* beta  = (const float*)d_in[2];
  const float* w_pos = (const float*)d_in[3];
  const float* w_tok = (const float*)d_in[4];
  const float* bt    = (const float*)d_in[5];
  float* out = (float*)d_out;
  float* ws  = (float*)d_ws;
  const unsigned M1 = 1u << 20;
  const float IS = 11.313708498984761f;  // sqrt(2*dh)

  // Workspace (f32 units, 19M = 76 MB; overlays only on dead regions):
  float*    PE    = ws;                               // [0,1M)    dead after pack16
  _Float16* peH   = (_Float16*)(ws + 1 * M1);         // [1,1.5M)  dead after pos gemm
  _Float16* peL   = (_Float16*)(ws + 1 * M1 + M1/2);  // [1.5,2M)
  _Float16* wpH   = (_Float16*)(ws + 2 * M1);         // [2,3M)    dead after pos gemm
  _Float16* wpL   = (_Float16*)(ws + 3 * M1);         // [3,4M)
  u16*      posKH = (u16*)(ws + 4 * M1);              // [4,4.5M)  live -> pack_kf
  u16*      posKL = (u16*)(ws + 4 * M1 + M1/2);       // [4.5,5M)
  u16*      posQH = (u16*)(ws + 5 * M1);              // [5,5.5M)  live -> attn
  u16*      posQL = (u16*)(ws + 5 * M1 + M1/2);       // [5.5,6M)
  float*    XN    = ws + 6 * M1;                      // [6,10M)   dead after pack16
  _Float16* xnH   = (_Float16*)(ws + 10 * M1);        // [10,12M)  dead after tok gemm
  _Float16* xnL   = (_Float16*)(ws + 12 * M1);        // [12,14M)  dead after tok gemm
  _Float16* wtH   = (_Float16*)(ws + 14 * M1);        // [14,15.5M) dead after tok gemm
  _Float16* wtL   = (_Float16*)(ws + 15 * M1 + M1/2); // [15.5,17M)
  u16*      KH    = (u16*)(ws);                       // [0,2M)    over PE/peHL; live -> pack_kf
  u16*      KL    = (u16*)(ws + 2 * M1);              // [2,4M)    over wpHL; live -> pack_kf
  u16*      QH    = (u16*)(ws + 6 * M1);              // [6,8M)    over XN; live -> attn
  u16*      QL    = (u16*)(ws + 8 * M1);              // [8,10M)
  u16*      VH    = (u16*)(ws + 17 * M1);             // [17,19M)  dead after pack_v
  u16*      Vf    = (u16*)(ws + 10 * M1);             // [10,12M)  over xnH; live -> attn
  float*    btT   = ws + 12 * M1;                     // [12,12.25M) over xnL
  u16*      KpfH  = (u16*)(ws + 12 * M1 + M1/4);      // [12.25,12.75M) 2 MB
  u16*      KpfL  = (u16*)(ws + 12 * M1 + 3*M1/4);    // [12.75,13.25M)
  u16*      KtfH  = (u16*)(ws + 13 * M1 + M1/4);      // [13.25,15.25M) 8 MB
  u16*      KtfL  = (u16*)(ws + 15 * M1 + M1/4);      // [15.25,17.25M)

  pe_kernel<<<SB, 256, 0, stream>>>(PE);
  pack16<<<SB / 16, 256, 0, stream>>>(PE, peH, peL, 1.0f);
  pack16<<<(2 * DM) / 16, 256, 0, stream>>>(w_pos, wpH, wpL, 32.0f);
  gemm16<<<dim3((2 * DM) / GBN, SB / GBM), 256, 0, stream>>>(
      peH, peL, wpH, wpL,
      posKH, posKL, 1.0f / 32.0f,
      posQH, posQL, IS / 32.0f,
      posKH, posKL, 1.0f / 32.0f);
  ln_kernel<<<BB * SB, 256, 0, stream>>>(x, gamma, beta, XN);
  pack16<<<(BB * SB) / 16, 256, 0, stream>>>(XN, xnH, xnL, 1.0f);
  pack16<<<(3 * DM) / 16, 256, 0, stream>>>(w_tok, wtH, wtL, 32.0f);
  gemm16<<<dim3((3 * DM) / GBN, (BB * SB) / GBM), 256, 0, stream>>>(
      xnH, xnL, wtH, wtL,
      KH, KL, 1.0f / 32.0f,
      QH, QL, IS / 32.0f,
      VH, (u16*)nullptr, 1.0f / 32.0f);
  pack_v<<<dim3(SB / 64, NH, BB), 256, 0, stream>>>(VH, Vf);   // must precede pack_kf (KtfL overlays VH head)
  pack_kf<<<dim3(4, NH, BB + 1), 256, 0, stream>>>(KH, KL, posKH, posKL,
                                                   KtfH, KtfL, KpfH, KpfL);
  btt_kernel<<<NH, 256, 0, stream>>>(bt, btT);
  attn_mfma4<<<BB * NH * (SB / 64), 256, 0, stream>>>(
      KtfH, KtfL, KpfH, KpfL, QH, QL, posQH, posQL, Vf, btT, out);
}